// Round 15
// baseline (319.123 us; speedup 1.0000x reference)
//
#include <hip/hip_runtime.h>
#include <math.h>

#define NSEQ 2048
#define NPOS 4095   // 2*NSEQ-1
#define NH   8
#define LOG2E 1.4426950408889634f

typedef _Float16 f16;
typedef f16 f16x8 __attribute__((ext_vector_type(8)));
typedef f16 f16x4 __attribute__((ext_vector_type(4)));
typedef float f32x4 __attribute__((ext_vector_type(4)));

#define MFMA16(a,b,c) __builtin_amdgcn_mfma_f32_16x16x32_f16(a,b,c,0,0,0)
// swizzled LDS byte offset: row stride 128B, 16B-granule XOR on (row&7)
#define LSWZ(row, col) (((row) << 7) + ((((col) << 1)) ^ (((row) & 7) << 4)))

__device__ __forceinline__ f16x8 cvt8(float4 a, float4 b) {
  f16x8 r = {(f16)a.x, (f16)a.y, (f16)a.z, (f16)a.w,
             (f16)b.x, (f16)b.y, (f16)b.z, (f16)b.w};
  return r;
}
__device__ __forceinline__ f16x8 scale8(f16x8 v, float4 a, float4 b) {
  f16x8 r;
  r[0] = (f16)((float)v[0] * a.x); r[1] = (f16)((float)v[1] * a.y);
  r[2] = (f16)((float)v[2] * a.z); r[3] = (f16)((float)v[3] * a.w);
  r[4] = (f16)((float)v[4] * b.x); r[5] = (f16)((float)v[5] * b.y);
  r[6] = (f16)((float)v[6] * b.z); r[7] = (f16)((float)v[7] * b.w);
  return r;
}

// ---------------- positional embedding pos[NPOS][192], one lane per (t,f) ----
__global__ __launch_bounds__(256) void pos_embed_k(float* __restrict__ pos) {
  int t = blockIdx.x * 8 + (threadIdx.x >> 5);
  int f = threadIdx.x & 31;
  if (t >= NPOS) return;
  float dist = (float)(t - (NSEQ - 1));
  float ad = fabsf(dist);
  float sgn = (dist > 0.f) ? 1.f : ((dist < 0.f) ? -1.f : 0.f);
  double mean = 64.0 * (double)(f + 1);       // linspace(64,2048,32)
  double conc = (mean / 32.0) * (mean / 32.0);
  double rate = mean / 1024.0;
  double p = 0.0;
  if (ad > 0.f) {
    double lu = (conc - 1.0) * log((double)ad) - rate * (double)ad;
    double ln = lgamma(conc) - conc * log(rate);
    p = exp(lu - ln);
  }
  float pf = (float)p + 1e-8f;
  float gmax = pf;
  #pragma unroll
  for (int mk = 1; mk <= 16; mk <<= 1) gmax = fmaxf(gmax, __shfl_xor(gmax, mk));
  float fg = pf / gmax;
  float hl = exp2f(3.f + 8.f * (float)f * (1.f / 31.f));
  float fe = exp2f(-ad / hl);
  float cw = exp2f((float)(f + 1)) - 1.f;
  float fc = (cw > ad) ? 1.f : 0.f;
  float* row = pos + (size_t)t * 192;
  row[f]       = fe;       row[32 + f]  = fc;       row[64 + f]  = fg;
  row[96 + f]  = sgn * fe; row[128 + f] = sgn * fc; row[160 + f] = sgn * fg;
}

// ---------------- relq = pos @ Wrel -> f16 [h][NPOS][64], scaled by log2e ---
__global__ __launch_bounds__(256) void relq_k(
    const float* __restrict__ A, const float* __restrict__ W, f16* __restrict__ relq)
{
  __shared__ f16 As[64][56];
  __shared__ f16 Bs[64][56];
  int tid = threadIdx.x, w = tid >> 6, lane = tid & 63, lr = lane >> 4, lc = lane & 15;
  int m0 = blockIdx.y * 64, n0 = blockIdx.x * 64;
  int ar = tid >> 2, ac = (tid & 3) * 8;
  int bk = tid >> 3, bn = (tid & 7) * 8;
  f32x4 acc[4] = {};
  for (int k0 = 0; k0 < 192; k0 += 32) {
    float4 a0 = make_float4(0.f,0.f,0.f,0.f), a1 = a0;
    if (m0 + ar < NPOS) {
      const float* ap = &A[(size_t)(m0 + ar) * 192 + k0 + ac];
      a0 = *(const float4*)ap; a1 = *(const float4*)(ap + 4);
    }
    *(f16x8*)&As[ar][ac] = cvt8(a0, a1);
    const float* bp = &W[(size_t)(k0 + bk) * 512 + n0 + bn];
    float4 b0 = *(const float4*)bp, b1 = *(const float4*)(bp + 4);
    f16 bv[8] = {(f16)b0.x,(f16)b0.y,(f16)b0.z,(f16)b0.w,(f16)b1.x,(f16)b1.y,(f16)b1.z,(f16)b1.w};
    #pragma unroll
    for (int tt = 0; tt < 8; tt++) { int t = (tt + bk) & 7; Bs[bn + t][bk] = bv[t]; }
    __syncthreads();
    f16x8 af = *(const f16x8*)&As[16*w + lc][8*lr];
    #pragma unroll
    for (int nt = 0; nt < 4; nt++) {
      f16x8 bf = *(const f16x8*)&Bs[16*nt + lc][8*lr];
      acc[nt] = MFMA16(af, bf, acc[nt]);
    }
    __syncthreads();
  }
  #pragma unroll
  for (int nt = 0; nt < 4; nt++)
    #pragma unroll
    for (int r = 0; r < 4; r++) {
      int m = m0 + 16*w + 4*lr + r;
      if (m >= NPOS) continue;
      int nn = n0 + 16*nt + lc;
      relq[((size_t)(nn >> 6) * NPOS + m) * 64 + (nn & 63)] = (f16)(acc[nt][r] * LOG2E);
    }
}

// ---------------- input projections (64x64 tile): A[4096,KD] x (W1|W2) -----
// first half  -> O1 head-split; SC1? (*0.125+rpb) : (*log2e)  [kb vs q]
// second half -> O2t TRANSPOSED [bh][d][2048]
template<int KD, bool SC1>
__global__ __launch_bounds__(256) void projx_k(
    const float* __restrict__ A, const float* __restrict__ W1, const float* __restrict__ W2,
    f16* __restrict__ O1, f16* __restrict__ O2t, const float* __restrict__ rpb)
{
  __shared__ f16 As[64][56];
  __shared__ f16 Bs[64][56];
  int tid = threadIdx.x, w = tid >> 6, lane = tid & 63, lr = lane >> 4, lc = lane & 15;
  int m0 = blockIdx.y * 64, n0g = blockIdx.x * 64;
  bool first = (n0g < 512);
  const float* W = first ? W1 : W2;
  int n0 = n0g & 511;
  int ar = tid >> 2, ac = (tid & 3) * 8;
  int bk = tid >> 3, bn = (tid & 7) * 8;
  f32x4 acc[4] = {};
  for (int k0 = 0; k0 < KD; k0 += 32) {
    const float* ap = &A[(size_t)(m0 + ar) * KD + k0 + ac];
    *(f16x8*)&As[ar][ac] = cvt8(*(const float4*)ap, *(const float4*)(ap + 4));
    const float* bp = &W[(size_t)(k0 + bk) * 512 + n0 + bn];
    float4 b0 = *(const float4*)bp, b1 = *(const float4*)(bp + 4);
    f16 bv[8] = {(f16)b0.x,(f16)b0.y,(f16)b0.z,(f16)b0.w,(f16)b1.x,(f16)b1.y,(f16)b1.z,(f16)b1.w};
    #pragma unroll
    for (int tt = 0; tt < 8; tt++) { int t = (tt + bk) & 7; Bs[bn + t][bk] = bv[t]; }
    __syncthreads();
    f16x8 af = *(const f16x8*)&As[16*w + lc][8*lr];
    #pragma unroll
    for (int nt = 0; nt < 4; nt++) {
      f16x8 bf = *(const f16x8*)&Bs[16*nt + lc][8*lr];
      acc[nt] = MFMA16(af, bf, acc[nt]);
    }
    __syncthreads();
  }
  if (first) {
    #pragma unroll
    for (int nt = 0; nt < 4; nt++)
      #pragma unroll
      for (int r = 0; r < 4; r++) {
        int m = m0 + 16*w + 4*lr + r;
        int nn = n0 + 16*nt + lc;
        float vv = acc[nt][r];
        if (SC1) vv = vv * 0.125f + rpb[nn];
        else     vv = vv * LOG2E;
        O1[(((size_t)((m >> 11) * NH + (nn >> 6))) * NSEQ + (m & (NSEQ - 1))) * 64 + (nn & 63)] = (f16)vv;
      }
  } else {
    int mb = m0 + 16*w + 4*lr;
    #pragma unroll
    for (int nt = 0; nt < 4; nt++) {
      int nn = n0 + 16*nt + lc;
      f16x4 pk = {(f16)acc[nt][0], (f16)acc[nt][1], (f16)acc[nt][2], (f16)acc[nt][3]};
      *(f16x4*)&O2t[(((size_t)((mb >> 11) * NH + (nn >> 6))) * 64 + (nn & 63)) * NSEQ + (mb & (NSEQ - 1))] = pk;
    }
  }
}

// ---------------- fused output projections (64x64 tile) ----------------
__global__ __launch_bounds__(256) void outproj_k(
    const f16* __restrict__ o1, const f16* __restrict__ o2,
    const float* __restrict__ Wo1, const float* __restrict__ Wo2,
    const float* __restrict__ bo1, const float* __restrict__ bo2,
    float* __restrict__ out)
{
  __shared__ f16 As[64][56];
  __shared__ f16 Bs[64][56];
  int by = blockIdx.y;
  bool first = (by < 64);
  const f16* A = first ? o1 : o2;
  const float* W = first ? Wo1 : Wo2;
  const float* bias = first ? bo1 : bo2;
  float* O = out + (first ? 0 : (size_t)4096 * 1024);
  int tid = threadIdx.x, w = tid >> 6, lane = tid & 63, lr = lane >> 4, lc = lane & 15;
  int m0 = (by & 63) * 64, n0 = blockIdx.x * 64;
  int ar = tid >> 2, ac = (tid & 3) * 8;
  int bk = tid >> 3, bn = (tid & 7) * 8;
  f32x4 acc[4] = {};
  for (int k0 = 0; k0 < 512; k0 += 32) {
    *(f16x8*)&As[ar][ac] = *(const f16x8*)&A[(size_t)(m0 + ar) * 512 + k0 + ac];
    const float* bp = &W[(size_t)(k0 + bk) * 1024 + n0 + bn];
    float4 b0 = *(const float4*)bp, b1 = *(const float4*)(bp + 4);
    f16 bv[8] = {(f16)b0.x,(f16)b0.y,(f16)b0.z,(f16)b0.w,(f16)b1.x,(f16)b1.y,(f16)b1.z,(f16)b1.w};
    #pragma unroll
    for (int tt = 0; tt < 8; tt++) { int t = (tt + bk) & 7; Bs[bn + t][bk] = bv[t]; }
    __syncthreads();
    f16x8 af = *(const f16x8*)&As[16*w + lc][8*lr];
    #pragma unroll
    for (int nt = 0; nt < 4; nt++) {
      f16x8 bf = *(const f16x8*)&Bs[16*nt + lc][8*lr];
      acc[nt] = MFMA16(af, bf, acc[nt]);
    }
    __syncthreads();
  }
  #pragma unroll
  for (int nt = 0; nt < 4; nt++)
    #pragma unroll
    for (int r = 0; r < 4; r++) {
      int m = m0 + 16*w + 4*lr + r;
      int n = n0 + 16*nt + lc;
      O[(size_t)m * 1024 + n] = acc[nt][r] + bias[n];
    }
}

// ---------------- fused logits + online softmax + out1 PV (8-wave) --------
// Log2-domain logits. 512-thread block: group 0 (waves 0-3) handles jt 0..15,
// group 1 (waves 4-7) handles jt 16..31 — doubles waves/CU vs 4-wave blocks
// at the grid-limited 2 blocks/CU. Per-tile body identical to round-14.
// Epilogue merges the two groups' (m, s, o1a) in LDS (no global round-trip).
// LDS 81920 B layout:
//   G2A@0 (Q stage + grp0 G2, 8K), G2B@8192 (grp1 G2, 8K),
//   grp g at 16384+g*32768: KB(+PW)@+0, VS@+8192, R0@+16384, R1@+24576.
//   Epilogue overlays: o1x f32[64][64] @32768 (grp0 R0+R1), stats @65536.
__global__ __launch_bounds__(512) void attn_k(
    const f16* __restrict__ q, const f16* __restrict__ kb,
    const f16* __restrict__ relq, const f16* __restrict__ v2t,
    f16* __restrict__ attnT, float* __restrict__ fac_t,
    f16* __restrict__ o1acc, int bh0)
{
  __shared__ char smem[81920];
  char* G2A = smem;
  int z = blockIdx.y, bh = bh0 + z, b = bh >> 3, h = bh & 7;
  int i0 = blockIdx.x * 64;
  int tid = threadIdx.x;
  int wg = tid >> 8;                 // group 0/1
  int tg = tid & 255;                // tid within group
  int w4 = (tid >> 6) & 3;           // wave within group
  int lane = tid & 63, lr = lane >> 4, lc = lane & 15;
  char* GRP = smem + 16384 + wg * 32768;
  char* KB = GRP;
  char* VS = GRP + 8192;
  char* R0 = GRP + 16384;
  char* R1 = GRP + 24576;
  char* G2 = smem + wg * 8192;       // G2A / G2B
  char* PW = KB + w4 * 2048;         // per-wave [16] swizzled rows
  int jt0 = wg * 16;
  int base0 = i0 + 1984;             // (NSEQ-1) + i0 - 63
  int row = tg >> 2, c0 = (tg & 3) * 16;

  if (tid < 256) {                   // stage Q once (into G2A region)
    const f16* qp = q + ((size_t)bh * NSEQ + i0 + row) * 64 + c0;
    *(f16x8*)(G2A + LSWZ(row, c0))     = *(const f16x8*)qp;
    *(f16x8*)(G2A + LSWZ(row, c0 + 8)) = *(const f16x8*)(qp + 8);
  }
  {  // prologue: panel jt0-1 -> R1 (jt0 even)
    const f16* rp = relq + ((size_t)h * NPOS + base0 + 64 - 64*jt0 + row) * 64 + c0;
    *(f16x8*)(R1 + LSWZ(row, c0))     = *(const f16x8*)rp;
    *(f16x8*)(R1 + LSWZ(row, c0 + 8)) = *(const f16x8*)(rp + 8);
  }
  __syncthreads();
  f16x8 qa0 = *(const f16x8*)(G2A + LSWZ(16*w4 + lc, 8*lr));
  f16x8 qa1 = *(const f16x8*)(G2A + LSWZ(16*w4 + lc, 32 + 8*lr));

  // tile-jt0 prefetch registers
  const f16* kpb  = kb  + ((size_t)bh * NSEQ + jt0 * 64 + row) * 64 + c0;
  const f16* vpb  = v2t + ((size_t)bh * 64 + row) * NSEQ + jt0 * 64 + c0;
  const f16* rpb0 = relq + ((size_t)h * NPOS + base0 - 64*jt0 + row) * 64 + c0;
  f16x8 skb0 = *(const f16x8*)kpb,  skb1 = *(const f16x8*)(kpb + 8);
  f16x8 sv0  = *(const f16x8*)vpb,  sv1  = *(const f16x8*)(vpb + 8);
  f16x8 sr0  = *(const f16x8*)rpb0, sr1  = *(const f16x8*)(rpb0 + 8);

  float m_run[4], ssum[4], mreg[4] = {};
  f32x4 o1a[4] = {};
  #pragma unroll
  for (int r = 0; r < 4; r++) { m_run[r] = -1e30f; ssum[r] = 0.f; }

  for (int jt = jt0; jt < jt0 + 16; jt++) {
    int j0 = jt * 64;
    char* RsA = (jt & 1) ? R1 : R0;   // panel jt: n in [0,64)
    char* RsB = (jt & 1) ? R0 : R1;   // panel jt-1: n in [64,128)
    *(f16x8*)(KB + LSWZ(row, c0))      = skb0;  *(f16x8*)(KB + LSWZ(row, c0 + 8))  = skb1;
    *(f16x8*)(VS + LSWZ(row, c0))      = sv0;   *(f16x8*)(VS + LSWZ(row, c0 + 8))  = sv1;
    *(f16x8*)(RsA + LSWZ(row, c0))     = sr0;   *(f16x8*)(RsA + LSWZ(row, c0 + 8)) = sr1;
    __syncthreads();   // s1: staging visible
    f32x4 cacc[4];
    f16x8 ka0 = {}, ka1 = {};
    __builtin_amdgcn_s_setprio(1);
    #pragma unroll
    for (int y = 0; y < 4; y++) {
      f16x8 b0 = *(const f16x8*)(KB + LSWZ(16*y + lc, 8*lr));
      f16x8 b1 = *(const f16x8*)(KB + LSWZ(16*y + lc, 32 + 8*lr));
      f32x4 t = {};
      t = MFMA16(qa0, b0, t);
      t = MFMA16(qa1, b1, t);
      cacc[y] = t;
      if (y == w4) { ka0 = b0; ka1 = b1; }
    }
    __builtin_amdgcn_s_setprio(0);
    // G blocks: only g in [3-w4, 7-w4] contribute
    #pragma unroll
    for (int gg = 0; gg < 5; gg++) {
      int g = 3 - w4 + gg;
      char* Rg = (g < 4) ? RsA : RsB;
      int grow = 16 * (g & 3) + lc;
      f32x4 ga = {};
      ga = MFMA16(ka0, *(const f16x8*)(Rg + LSWZ(grow, 8*lr)), ga);
      ga = MFMA16(ka1, *(const f16x8*)(Rg + LSWZ(grow, 32 + 8*lr)), ga);
      int jj = 16*w4 + 4*lr;
      #pragma unroll
      for (int r = 0; r < 4; r++) {
        int ii = 16*g + lc + jj + r - 63;   // i = n + j - 63
        if ((unsigned)ii < 64u) *(f16*)(G2 + LSWZ(jj + r, ii)) = (f16)ga[r];
      }
    }
    // prefetch next tile into registers (hides under softmax+PV)
    {
      int jn = (jt < jt0 + 15) ? jt + 1 : jt;
      const f16* kpn = kb  + ((size_t)bh * NSEQ + jn * 64 + row) * 64 + c0;
      const f16* vpn = v2t + ((size_t)bh * 64 + row) * NSEQ + jn * 64 + c0;
      const f16* rpn = relq + ((size_t)h * NPOS + base0 - 64 * jn + row) * 64 + c0;
      skb0 = *(const f16x8*)kpn;  skb1 = *(const f16x8*)(kpn + 8);
      sv0  = *(const f16x8*)vpn;  sv1  = *(const f16x8*)(vpn + 8);
      sr0  = *(const f16x8*)rpn;  sr1  = *(const f16x8*)(rpn + 8);
    }
    __syncthreads();   // s2: G2 complete; KB frag reads done -> PW overlay safe
    float l[4][4];
    #pragma unroll
    for (int y = 0; y < 4; y++) {
      f16x4 gv = *(const f16x4*)(G2 + LSWZ(16*y + lc, 16*w4 + 4*lr));
      #pragma unroll
      for (int r = 0; r < 4; r++) l[y][r] = cacc[y][r] + (float)gv[r];
    }
    float pvr[4][4];   // [r][y]
    #pragma unroll
    for (int r = 0; r < 4; r++) {
      float tm = fmaxf(fmaxf(l[0][r], l[1][r]), fmaxf(l[2][r], l[3][r]));
      #pragma unroll
      for (int mk = 1; mk <= 8; mk <<= 1) tm = fmaxf(tm, __shfl_xor(tm, mk));
      if (tm > m_run[r]) {
        float sc = exp2f(m_run[r] - tm);
        ssum[r] *= sc;
        #pragma unroll
        for (int nt = 0; nt < 4; nt++) o1a[nt][r] *= sc;
        m_run[r] = tm;
      }
      float mnew = m_run[r];
      float ps = 0.f;
      #pragma unroll
      for (int y = 0; y < 4; y++) {
        float p = exp2f(l[y][r] - mnew);
        ps += p;
        pvr[r][y] = p;
        *(f16*)(PW + LSWZ(4*lr + r, 16*y + lc)) = (f16)p;
      }
      ssum[r] += ps;
      if (lc == jt - jt0) mreg[r] = mnew;   // lane lc owns tile jt0+lc
    }
    // transposed P store, direct from registers: attnT[j][i]
    #pragma unroll
    for (int y = 0; y < 4; y++) {
      f16x4 pk = {(f16)pvr[0][y], (f16)pvr[1][y], (f16)pvr[2][y], (f16)pvr[3][y]};
      *(f16x4*)&attnT[((size_t)z * NSEQ + j0 + 16*y + lc) * NSEQ + i0 + 16*w4 + 4*lr] = pk;
    }
    // out1 PV (PW per-wave, lgkmcnt-ordered)
    {
      f16x8 pa0 = *(const f16x8*)(PW + LSWZ(lc, 8*lr));
      f16x8 pa1 = *(const f16x8*)(PW + LSWZ(lc, 32 + 8*lr));
      __builtin_amdgcn_s_setprio(1);
      #pragma unroll
      for (int nt = 0; nt < 4; nt++) {
        f16x8 vf0 = *(const f16x8*)(VS + LSWZ(16*nt + lc, 8*lr));
        f16x8 vf1 = *(const f16x8*)(VS + LSWZ(16*nt + lc, 32 + 8*lr));
        o1a[nt] = MFMA16(pa0, vf0, o1a[nt]);
        o1a[nt] = MFMA16(pa1, vf1, o1a[nt]);
      }
      __builtin_amdgcn_s_setprio(0);
    }
    __syncthreads();   // s3: all LDS reads done -> restage ok
  }
  // ---------------- epilogue: merge the two groups in LDS ----------------
  float* stats = (float*)(smem + 65536);   // [2][64][2] f32 (grp1 R0, dead)
  float* o1x   = (float*)(smem + 32768);   // [64][64] f32 (grp0 R0+R1, dead)
  float invs[4], mfin[4];
  #pragma unroll
  for (int r = 0; r < 4; r++) {
    float s = ssum[r];
    #pragma unroll
    for (int mk = 1; mk <= 8; mk <<= 1) s += __shfl_xor(s, mk);
    int il = 16*w4 + 4*lr + r;
    if (lc == 0) { stats[(wg*64 + il)*2] = m_run[r]; stats[(wg*64 + il)*2 + 1] = s; }
  }
  __syncthreads();
  #pragma unroll
  for (int r = 0; r < 4; r++) {
    int il = 16*w4 + 4*lr + r;
    float m0v = stats[il*2],        s0v = stats[il*2 + 1];
    float m1v = stats[(64+il)*2],   s1v = stats[(64+il)*2 + 1];
    float mf = fmaxf(m0v, m1v);
    float sf = s0v * exp2f(m0v - mf) + s1v * exp2f(m1v - mf);
    mfin[r] = mf; invs[r] = 1.f / sf;
    float fv = exp2f(mreg[r] - mf) * invs[r];   // this group's tile jt0+lc
    fac_t[((size_t)z * 32 + jt0 + lc) * NSEQ + i0 + il] = fv;
  }
  if (wg == 1) {
    #pragma unroll
    for (int nt = 0; nt < 4; nt++)
      #pragma unroll
      for (int r = 0; r < 4; r++) {
        int il = 16*w4 + 4*lr + r;
        o1x[il*64 + 16*nt + lc] = o1a[nt][r] * exp2f(m_run[r] - mfin[r]);
      }
  }
  __syncthreads();
  if (wg == 0) {
    #pragma unroll
    for (int nt = 0; nt < 4; nt++)
      #pragma unroll
      for (int r = 0; r < 4; r++) {
        int il = 16*w4 + 4*lr + r;
        float val = (o1a[nt][r] * exp2f(m_run[r] - mfin[r]) + o1x[il*64 + 16*nt + lc]) * invs[r];
        o1acc[((size_t)b * NSEQ + i0 + il) * 512 + h * 64 + 16*nt + lc] = (f16)val;
      }
  }
}

// ---------------- pv2: out2[j,d] = sum_i attnT[j,i]*fac_t[jt,i]*v1[i,d] ----
// A-fragments straight from global attnT (no LDS); Vs = v1t rows scaled by
// fac_t at staging (swizzled b128, conflict-free).
__global__ __launch_bounds__(256) void pv2_k(const f16* __restrict__ attnT,
    const f16* __restrict__ v1t, const float* __restrict__ fac_t,
    f16* __restrict__ oacc, int bh0)
{
  __shared__ char vsm[8192];   // Vs [64] swizzled rows: [d][k=i]
  int z = blockIdx.y, bh = bh0 + z, b = bh >> 3, h = bh & 7;
  int r0 = blockIdx.x * 64;    // j-block == jt index
  int tid = threadIdx.x, w = tid >> 6, lane = tid & 63;
  int lr = lane >> 4, lc = lane & 15;
  int row = tid >> 2, cv = (tid & 3) * 16;
  const f16* vp = v1t + ((size_t)bh * 64 + row) * NSEQ + cv;
  const float* fp = fac_t + ((size_t)z * 32 + blockIdx.x) * NSEQ + cv;
  const f16* ap = attnT + ((size_t)z * NSEQ + r0 + 16*w + lc) * NSEQ + 8*lr;
  f32x4 acc[4] = {};
  for (int k0 = 0; k0 < NSEQ; k0 += 64) {
    f16x8 v0 = *(const f16x8*)(vp + k0);
    f16x8 v1 = *(const f16x8*)(vp + k0 + 8);
    float4 f0 = *(const float4*)(fp + k0),     f1 = *(const float4*)(fp + k0 + 4);
    float4 f2 = *(const float4*)(fp + k0 + 8), f3 = *(const float4*)(fp + k0 + 12);
    *(f16x8*)(vsm + LSWZ(row, cv))     = scale8(v0, f0, f1);
    *(f16x8*)(vsm + LSWZ(row, cv + 8)) = scale8(v1, f2, f3);
    __syncthreads();
    f16x8 a0 = *(const f16x8*)(ap + k0);
    f16x8 a1 = *(const f16x8*)(ap + k0 + 32);
    #pragma unroll
    for (int nt = 0; nt < 4; nt++) {
      acc[nt] = MFMA16(a0, *(const f16x8*)(vsm + LSWZ(16*nt + lc, 8*lr)), acc[nt]);
      acc[nt] = MFMA16(a1, *(const f16x8*)(vsm + LSWZ(16*nt + lc, 32 + 8*lr)), acc[nt]);
    }
    __syncthreads();
  }
  #pragma unroll
  for (int nt = 0; nt < 4; nt++)
    #pragma unroll
    for (int r = 0; r < 4; r++) {
      int rw = r0 + 16*w + 4*lr + r;
      oacc[((size_t)b * NSEQ + rw) * 512 + h * 64 + 16*nt + lc] = (f16)acc[nt][r];
    }
}

extern "C" void kernel_launch(void* const* d_in, const int* in_sizes, int n_in,
                              void* d_out, int out_size, void* d_ws, size_t ws_size,
                              hipStream_t stream) {
  const float* x1   = (const float*)d_in[0];
  const float* x2   = (const float*)d_in[1];
  const float* Wq   = (const float*)d_in[2];
  const float* Wk   = (const float*)d_in[3];
  const float* Wv1  = (const float*)d_in[4];
  const float* Wv2  = (const float*)d_in[5];
  const float* Wrel = (const float*)d_in[6];
  const float* rpb  = (const float*)d_in[7];
  const float* Wo1  = (const float*)d_in[8];
  const float* bo1  = (const float*)d_in[9];
  const float* Wo2  = (const float*)d_in[10];
  const float* bo2  = (const float*)d_in[11];
  float* out = (float*)d_out;

  char* base = (char*)d_ws;
  size_t off = 0;
  auto alloc = [&](size_t bytes) -> void* {
    void* p = base + off; off += (bytes + 255) & ~(size_t)255; return p;
  };
  float* pos   = (float*)alloc((size_t)NPOS * 192 * 4);
  f16*   relq  = (f16*)  alloc((size_t)NH * NPOS * 64 * 2);
  f16*   qh    = (f16*)  alloc((size_t)16 * NSEQ * 64 * 2);
  f16*   kbh   = (f16*)  alloc((size_t)16 * NSEQ * 64 * 2);
  f16*   v1t   = (f16*)  alloc((size_t)16 * 64 * NSEQ * 2);
  f16*   v2t   = (f16*)  alloc((size_t)16 * 64 * NSEQ * 2);
  f16*   o1acc = (f16*)  alloc((size_t)2 * NSEQ * 512 * 2);
  f16*   o2acc = (f16*)  alloc((size_t)2 * NSEQ * 512 * 2);
  float* fac_t = (float*)alloc((size_t)16 * 32 * NSEQ * 4);
  size_t baseB = off;

  int chunk = 1;
  for (int c = 16; c >= 1; c >>= 1) {
    size_t needB = baseB + (size_t)c * NSEQ * NSEQ * 2;
    if (needB <= ws_size) { chunk = c; break; }
  }
  f16* attnT = (f16*)(base + baseB);

  pos_embed_k<<<(NPOS + 7) / 8, 256, 0, stream>>>(pos);
  relq_k<<<dim3(8, 64), 256, 0, stream>>>(pos, Wrel, relq);
  projx_k<1024, false><<<dim3(16, 64), 256, 0, stream>>>(x1, Wq, Wv1, qh, v1t, nullptr);
  projx_k<512,  true ><<<dim3(16, 64), 256, 0, stream>>>(x2, Wk, Wv2, kbh, v2t, rpb);

  for (int bh0 = 0; bh0 < 16; bh0 += chunk) {
    attn_k<<<dim3(32, chunk), 512, 0, stream>>>(qh, kbh, relq, v2t, attnT, fac_t, o1acc, bh0);
    pv2_k<<<dim3(32, chunk), 256, 0, stream>>>(attnT, v1t, fac_t, o2acc, bh0);
  }

  outproj_k<<<dim3(16, 128), 256, 0, stream>>>(o1acc, o2acc, Wo1, Wo2, bo1, bo2, out);
}

// Round 16
// 300.008 us; speedup vs baseline: 1.0637x; 1.0637x over previous
//
#include <hip/hip_runtime.h>
#include <math.h>

#define NSEQ 2048
#define NPOS 4095   // 2*NSEQ-1
#define NH   8
#define LOG2E 1.4426950408889634f

typedef _Float16 f16;
typedef f16 f16x8 __attribute__((ext_vector_type(8)));
typedef f16 f16x4 __attribute__((ext_vector_type(4)));
typedef float f32x4 __attribute__((ext_vector_type(4)));

#define MFMA16(a,b,c) __builtin_amdgcn_mfma_f32_16x16x32_f16(a,b,c,0,0,0)
// swizzled LDS byte offset: row stride 128B, 16B-granule XOR on (row&7)
#define LSWZ(row, col) (((row) << 7) + ((((col) << 1)) ^ (((row) & 7) << 4)))

__device__ __forceinline__ f16x8 cvt8(float4 a, float4 b) {
  f16x8 r = {(f16)a.x, (f16)a.y, (f16)a.z, (f16)a.w,
             (f16)b.x, (f16)b.y, (f16)b.z, (f16)b.w};
  return r;
}
__device__ __forceinline__ f16x8 scale8(f16x8 v, float4 a, float4 b) {
  f16x8 r;
  r[0] = (f16)((float)v[0] * a.x); r[1] = (f16)((float)v[1] * a.y);
  r[2] = (f16)((float)v[2] * a.z); r[3] = (f16)((float)v[3] * a.w);
  r[4] = (f16)((float)v[4] * b.x); r[5] = (f16)((float)v[5] * b.y);
  r[6] = (f16)((float)v[6] * b.z); r[7] = (f16)((float)v[7] * b.w);
  return r;
}

// ---------------- positional embedding pos[NPOS][192], one lane per (t,f) ----
__global__ __launch_bounds__(256) void pos_embed_k(float* __restrict__ pos) {
  int t = blockIdx.x * 8 + (threadIdx.x >> 5);
  int f = threadIdx.x & 31;
  if (t >= NPOS) return;
  float dist = (float)(t - (NSEQ - 1));
  float ad = fabsf(dist);
  float sgn = (dist > 0.f) ? 1.f : ((dist < 0.f) ? -1.f : 0.f);
  double mean = 64.0 * (double)(f + 1);       // linspace(64,2048,32)
  double conc = (mean / 32.0) * (mean / 32.0);
  double rate = mean / 1024.0;
  double p = 0.0;
  if (ad > 0.f) {
    double lu = (conc - 1.0) * log((double)ad) - rate * (double)ad;
    double ln = lgamma(conc) - conc * log(rate);
    p = exp(lu - ln);
  }
  float pf = (float)p + 1e-8f;
  float gmax = pf;
  #pragma unroll
  for (int mk = 1; mk <= 16; mk <<= 1) gmax = fmaxf(gmax, __shfl_xor(gmax, mk));
  float fg = pf / gmax;
  float hl = exp2f(3.f + 8.f * (float)f * (1.f / 31.f));
  float fe = exp2f(-ad / hl);
  float cw = exp2f((float)(f + 1)) - 1.f;
  float fc = (cw > ad) ? 1.f : 0.f;
  float* row = pos + (size_t)t * 192;
  row[f]       = fe;       row[32 + f]  = fc;       row[64 + f]  = fg;
  row[96 + f]  = sgn * fe; row[128 + f] = sgn * fc; row[160 + f] = sgn * fg;
}

// ---------------- relq = pos @ Wrel -> f16 [h][NPOS][64], scaled by log2e ---
__global__ __launch_bounds__(256) void relq_k(
    const float* __restrict__ A, const float* __restrict__ W, f16* __restrict__ relq)
{
  __shared__ f16 As[64][56];
  __shared__ f16 Bs[64][56];
  int tid = threadIdx.x, w = tid >> 6, lane = tid & 63, lr = lane >> 4, lc = lane & 15;
  int m0 = blockIdx.y * 64, n0 = blockIdx.x * 64;
  int ar = tid >> 2, ac = (tid & 3) * 8;
  int bk = tid >> 3, bn = (tid & 7) * 8;
  f32x4 acc[4] = {};
  for (int k0 = 0; k0 < 192; k0 += 32) {
    float4 a0 = make_float4(0.f,0.f,0.f,0.f), a1 = a0;
    if (m0 + ar < NPOS) {
      const float* ap = &A[(size_t)(m0 + ar) * 192 + k0 + ac];
      a0 = *(const float4*)ap; a1 = *(const float4*)(ap + 4);
    }
    *(f16x8*)&As[ar][ac] = cvt8(a0, a1);
    const float* bp = &W[(size_t)(k0 + bk) * 512 + n0 + bn];
    float4 b0 = *(const float4*)bp, b1 = *(const float4*)(bp + 4);
    f16 bv[8] = {(f16)b0.x,(f16)b0.y,(f16)b0.z,(f16)b0.w,(f16)b1.x,(f16)b1.y,(f16)b1.z,(f16)b1.w};
    #pragma unroll
    for (int tt = 0; tt < 8; tt++) { int t = (tt + bk) & 7; Bs[bn + t][bk] = bv[t]; }
    __syncthreads();
    f16x8 af = *(const f16x8*)&As[16*w + lc][8*lr];
    #pragma unroll
    for (int nt = 0; nt < 4; nt++) {
      f16x8 bf = *(const f16x8*)&Bs[16*nt + lc][8*lr];
      acc[nt] = MFMA16(af, bf, acc[nt]);
    }
    __syncthreads();
  }
  #pragma unroll
  for (int nt = 0; nt < 4; nt++)
    #pragma unroll
    for (int r = 0; r < 4; r++) {
      int m = m0 + 16*w + 4*lr + r;
      if (m >= NPOS) continue;
      int nn = n0 + 16*nt + lc;
      relq[((size_t)(nn >> 6) * NPOS + m) * 64 + (nn & 63)] = (f16)(acc[nt][r] * LOG2E);
    }
}

// ---------------- input projections (64x64 tile): A[4096,KD] x (W1|W2) -----
// first half  -> O1 head-split; SC1? (*0.125+rpb) : (*log2e)  [kb vs q]
// second half -> O2t TRANSPOSED [bh][d][2048]
template<int KD, bool SC1>
__global__ __launch_bounds__(256) void projx_k(
    const float* __restrict__ A, const float* __restrict__ W1, const float* __restrict__ W2,
    f16* __restrict__ O1, f16* __restrict__ O2t, const float* __restrict__ rpb)
{
  __shared__ f16 As[64][56];
  __shared__ f16 Bs[64][56];
  int tid = threadIdx.x, w = tid >> 6, lane = tid & 63, lr = lane >> 4, lc = lane & 15;
  int m0 = blockIdx.y * 64, n0g = blockIdx.x * 64;
  bool first = (n0g < 512);
  const float* W = first ? W1 : W2;
  int n0 = n0g & 511;
  int ar = tid >> 2, ac = (tid & 3) * 8;
  int bk = tid >> 3, bn = (tid & 7) * 8;
  f32x4 acc[4] = {};
  for (int k0 = 0; k0 < KD; k0 += 32) {
    const float* ap = &A[(size_t)(m0 + ar) * KD + k0 + ac];
    *(f16x8*)&As[ar][ac] = cvt8(*(const float4*)ap, *(const float4*)(ap + 4));
    const float* bp = &W[(size_t)(k0 + bk) * 512 + n0 + bn];
    float4 b0 = *(const float4*)bp, b1 = *(const float4*)(bp + 4);
    f16 bv[8] = {(f16)b0.x,(f16)b0.y,(f16)b0.z,(f16)b0.w,(f16)b1.x,(f16)b1.y,(f16)b1.z,(f16)b1.w};
    #pragma unroll
    for (int tt = 0; tt < 8; tt++) { int t = (tt + bk) & 7; Bs[bn + t][bk] = bv[t]; }
    __syncthreads();
    f16x8 af = *(const f16x8*)&As[16*w + lc][8*lr];
    #pragma unroll
    for (int nt = 0; nt < 4; nt++) {
      f16x8 bf = *(const f16x8*)&Bs[16*nt + lc][8*lr];
      acc[nt] = MFMA16(af, bf, acc[nt]);
    }
    __syncthreads();
  }
  if (first) {
    #pragma unroll
    for (int nt = 0; nt < 4; nt++)
      #pragma unroll
      for (int r = 0; r < 4; r++) {
        int m = m0 + 16*w + 4*lr + r;
        int nn = n0 + 16*nt + lc;
        float vv = acc[nt][r];
        if (SC1) vv = vv * 0.125f + rpb[nn];
        else     vv = vv * LOG2E;
        O1[(((size_t)((m >> 11) * NH + (nn >> 6))) * NSEQ + (m & (NSEQ - 1))) * 64 + (nn & 63)] = (f16)vv;
      }
  } else {
    int mb = m0 + 16*w + 4*lr;
    #pragma unroll
    for (int nt = 0; nt < 4; nt++) {
      int nn = n0 + 16*nt + lc;
      f16x4 pk = {(f16)acc[nt][0], (f16)acc[nt][1], (f16)acc[nt][2], (f16)acc[nt][3]};
      *(f16x4*)&O2t[(((size_t)((mb >> 11) * NH + (nn >> 6))) * 64 + (nn & 63)) * NSEQ + (mb & (NSEQ - 1))] = pk;
    }
  }
}

// ---------------- fused output projections (64x64 tile) ----------------
__global__ __launch_bounds__(256) void outproj_k(
    const f16* __restrict__ o1, const f16* __restrict__ o2,
    const float* __restrict__ Wo1, const float* __restrict__ Wo2,
    const float* __restrict__ bo1, const float* __restrict__ bo2,
    float* __restrict__ out)
{
  __shared__ f16 As[64][56];
  __shared__ f16 Bs[64][56];
  int by = blockIdx.y;
  bool first = (by < 64);
  const f16* A = first ? o1 : o2;
  const float* W = first ? Wo1 : Wo2;
  const float* bias = first ? bo1 : bo2;
  float* O = out + (first ? 0 : (size_t)4096 * 1024);
  int tid = threadIdx.x, w = tid >> 6, lane = tid & 63, lr = lane >> 4, lc = lane & 15;
  int m0 = (by & 63) * 64, n0 = blockIdx.x * 64;
  int ar = tid >> 2, ac = (tid & 3) * 8;
  int bk = tid >> 3, bn = (tid & 7) * 8;
  f32x4 acc[4] = {};
  for (int k0 = 0; k0 < 512; k0 += 32) {
    *(f16x8*)&As[ar][ac] = *(const f16x8*)&A[(size_t)(m0 + ar) * 512 + k0 + ac];
    const float* bp = &W[(size_t)(k0 + bk) * 1024 + n0 + bn];
    float4 b0 = *(const float4*)bp, b1 = *(const float4*)(bp + 4);
    f16 bv[8] = {(f16)b0.x,(f16)b0.y,(f16)b0.z,(f16)b0.w,(f16)b1.x,(f16)b1.y,(f16)b1.z,(f16)b1.w};
    #pragma unroll
    for (int tt = 0; tt < 8; tt++) { int t = (tt + bk) & 7; Bs[bn + t][bk] = bv[t]; }
    __syncthreads();
    f16x8 af = *(const f16x8*)&As[16*w + lc][8*lr];
    #pragma unroll
    for (int nt = 0; nt < 4; nt++) {
      f16x8 bf = *(const f16x8*)&Bs[16*nt + lc][8*lr];
      acc[nt] = MFMA16(af, bf, acc[nt]);
    }
    __syncthreads();
  }
  #pragma unroll
  for (int nt = 0; nt < 4; nt++)
    #pragma unroll
    for (int r = 0; r < 4; r++) {
      int m = m0 + 16*w + 4*lr + r;
      int n = n0 + 16*nt + lc;
      O[(size_t)m * 1024 + n] = acc[nt][r] + bias[n];
    }
}

// ---------------- fused logits + online softmax + out1 PV ----------------
// Round-14 structure (4 waves, one block per (i0,z)) with double-buffered
// KB/VS (ping-pong on jt&1) + dedicated PW region -> 2 barriers/tile (was 3).
// Cross-tile hazards: every reader/writer pair of a given buffer is separated
// by >=1 full barrier (s1/s2 of the intervening tile) — barrier semantics
// force all waves past s2 before any wave starts the next tile's top writes.
// LDS 65536 B: QG(Q+G2)@0, KB0@8192, KB1@16384, VS0@24576, VS1@32768,
// R0@40960, R1@49152, PW@57344 (per-wave 2048B).
__global__ __launch_bounds__(256) void attn_k(
    const f16* __restrict__ q, const f16* __restrict__ kb,
    const f16* __restrict__ relq, const f16* __restrict__ v2t,
    f16* __restrict__ attnT, float* __restrict__ fac_t,
    f16* __restrict__ o1acc, int bh0)
{
  __shared__ char smem[65536];
  char* QG  = smem;
  char* KB0 = smem + 8192;
  char* KB1 = smem + 16384;
  char* VS0 = smem + 24576;
  char* VS1 = smem + 32768;
  char* R0  = smem + 40960;
  char* R1  = smem + 49152;
  int z = blockIdx.y, bh = bh0 + z, b = bh >> 3, h = bh & 7;
  int i0 = blockIdx.x * 64;
  int tid = threadIdx.x, w = tid >> 6, lane = tid & 63;
  int lr = lane >> 4, lc = lane & 15;
  char* PW = smem + 57344 + w * 2048;   // per-wave [16] swizzled rows
  int base0 = i0 + 1984;                // (NSEQ-1) + i0 - 63
  int row = tid >> 2, c0 = (tid & 3) * 16;

  {
    const f16* qp = q + ((size_t)bh * NSEQ + i0 + row) * 64 + c0;
    *(f16x8*)(QG + LSWZ(row, c0))     = *(const f16x8*)qp;
    *(f16x8*)(QG + LSWZ(row, c0 + 8)) = *(const f16x8*)(qp + 8);
    // prologue: panel -1 -> R1 (jt=0 uses RsA=R0, RsB=R1)
    const f16* rp = relq + ((size_t)h * NPOS + base0 + 64 + row) * 64 + c0;
    *(f16x8*)(R1 + LSWZ(row, c0))     = *(const f16x8*)rp;
    *(f16x8*)(R1 + LSWZ(row, c0 + 8)) = *(const f16x8*)(rp + 8);
  }
  __syncthreads();
  f16x8 qa0 = *(const f16x8*)(QG + LSWZ(16*w + lc, 8*lr));
  f16x8 qa1 = *(const f16x8*)(QG + LSWZ(16*w + lc, 32 + 8*lr));

  // tile-0 prefetch registers
  const f16* kpb  = kb  + ((size_t)bh * NSEQ + row) * 64 + c0;
  const f16* vpb  = v2t + ((size_t)bh * 64 + row) * NSEQ + c0;
  const f16* rpb0 = relq + ((size_t)h * NPOS + base0 + row) * 64 + c0;
  f16x8 skb0 = *(const f16x8*)kpb,  skb1 = *(const f16x8*)(kpb + 8);
  f16x8 sv0  = *(const f16x8*)vpb,  sv1  = *(const f16x8*)(vpb + 8);
  f16x8 sr0  = *(const f16x8*)rpb0, sr1  = *(const f16x8*)(rpb0 + 8);

  float m_run[4], ssum[4];
  float mreg0[4] = {}, mreg1[4] = {};
  f32x4 o1a[4] = {};
  #pragma unroll
  for (int r = 0; r < 4; r++) { m_run[r] = -1e30f; ssum[r] = 0.f; }

  for (int jt = 0; jt < 32; jt++) {
    int j0 = jt * 64;
    char* KB  = (jt & 1) ? KB1 : KB0;
    char* VS  = (jt & 1) ? VS1 : VS0;
    char* RsA = (jt & 1) ? R1 : R0;   // panel jt: n in [0,64)
    char* RsB = (jt & 1) ? R0 : R1;   // panel jt-1: n in [64,128)
    *(f16x8*)(KB + LSWZ(row, c0))      = skb0;  *(f16x8*)(KB + LSWZ(row, c0 + 8))  = skb1;
    *(f16x8*)(VS + LSWZ(row, c0))      = sv0;   *(f16x8*)(VS + LSWZ(row, c0 + 8))  = sv1;
    *(f16x8*)(RsA + LSWZ(row, c0))     = sr0;   *(f16x8*)(RsA + LSWZ(row, c0 + 8)) = sr1;
    __syncthreads();   // s1: staging visible; prev tile's G2 reads all done
    f32x4 cacc[4];
    f16x8 ka0 = {}, ka1 = {};
    __builtin_amdgcn_s_setprio(1);
    #pragma unroll
    for (int y = 0; y < 4; y++) {
      f16x8 b0 = *(const f16x8*)(KB + LSWZ(16*y + lc, 8*lr));
      f16x8 b1 = *(const f16x8*)(KB + LSWZ(16*y + lc, 32 + 8*lr));
      f32x4 t = {};
      t = MFMA16(qa0, b0, t);
      t = MFMA16(qa1, b1, t);
      cacc[y] = t;
      if (y == w) { ka0 = b0; ka1 = b1; }
    }
    __builtin_amdgcn_s_setprio(0);
    // G blocks: only g in [3-w, 7-w] contribute
    #pragma unroll
    for (int gg = 0; gg < 5; gg++) {
      int g = 3 - w + gg;
      char* Rg = (g < 4) ? RsA : RsB;
      int grow = 16 * (g & 3) + lc;
      f32x4 ga = {};
      ga = MFMA16(ka0, *(const f16x8*)(Rg + LSWZ(grow, 8*lr)), ga);
      ga = MFMA16(ka1, *(const f16x8*)(Rg + LSWZ(grow, 32 + 8*lr)), ga);
      int jj = 16*w + 4*lr;
      #pragma unroll
      for (int r = 0; r < 4; r++) {
        int ii = 16*g + lc + jj + r - 63;   // i = n + j - 63
        if ((unsigned)ii < 64u) *(f16*)(QG + LSWZ(jj + r, ii)) = (f16)ga[r];
      }
    }
    // prefetch next tile into registers (hides under softmax+PV)
    {
      int jn = (jt < 31) ? jt + 1 : 31;
      const f16* kpn = kb  + ((size_t)bh * NSEQ + jn * 64 + row) * 64 + c0;
      const f16* vpn = v2t + ((size_t)bh * 64 + row) * NSEQ + jn * 64 + c0;
      const f16* rpn = relq + ((size_t)h * NPOS + base0 - 64 * jn + row) * 64 + c0;
      skb0 = *(const f16x8*)kpn;  skb1 = *(const f16x8*)(kpn + 8);
      sv0  = *(const f16x8*)vpn;  sv1  = *(const f16x8*)(vpn + 8);
      sr0  = *(const f16x8*)rpn;  sr1  = *(const f16x8*)(rpn + 8);
    }
    __syncthreads();   // s2: G2 scatter complete; KB frag reads done
    float l[4][4];
    #pragma unroll
    for (int y = 0; y < 4; y++) {
      f16x4 gv = *(const f16x4*)(QG + LSWZ(16*y + lc, 16*w + 4*lr));
      #pragma unroll
      for (int r = 0; r < 4; r++) l[y][r] = cacc[y][r] + (float)gv[r];
    }
    float pvr[4][4];   // [r][y]
    #pragma unroll
    for (int r = 0; r < 4; r++) {
      float tm = fmaxf(fmaxf(l[0][r], l[1][r]), fmaxf(l[2][r], l[3][r]));
      #pragma unroll
      for (int mk = 1; mk <= 8; mk <<= 1) tm = fmaxf(tm, __shfl_xor(tm, mk));
      if (tm > m_run[r]) {
        float sc = exp2f(m_run[r] - tm);
        ssum[r] *= sc;
        #pragma unroll
        for (int nt = 0; nt < 4; nt++) o1a[nt][r] *= sc;
        m_run[r] = tm;
      }
      float mnew = m_run[r];
      float ps = 0.f;
      #pragma unroll
      for (int y = 0; y < 4; y++) {
        float p = exp2f(l[y][r] - mnew);
        ps += p;
        pvr[r][y] = p;
        *(f16*)(PW + LSWZ(4*lr + r, 16*y + lc)) = (f16)p;
      }
      ssum[r] += ps;
      // capture running max per tile in registers: lane lc owns jt=lc, 16+lc
      if (jt < 16) { if (lc == jt) mreg0[r] = mnew; }
      else         { if (lc == jt - 16) mreg1[r] = mnew; }
    }
    // transposed P store, direct from registers: attnT[j][i]
    #pragma unroll
    for (int y = 0; y < 4; y++) {
      f16x4 pk = {(f16)pvr[0][y], (f16)pvr[1][y], (f16)pvr[2][y], (f16)pvr[3][y]};
      *(f16x4*)&attnT[((size_t)z * NSEQ + j0 + 16*y + lc) * NSEQ + i0 + 16*w + 4*lr] = pk;
    }
    // out1 PV (PW per-wave, lgkmcnt-ordered; VS read completes before next
    // tile's s1 can be passed by any wave)
    {
      f16x8 pa0 = *(const f16x8*)(PW + LSWZ(lc, 8*lr));
      f16x8 pa1 = *(const f16x8*)(PW + LSWZ(lc, 32 + 8*lr));
      __builtin_amdgcn_s_setprio(1);
      #pragma unroll
      for (int nt = 0; nt < 4; nt++) {
        f16x8 vf0 = *(const f16x8*)(VS + LSWZ(16*nt + lc, 8*lr));
        f16x8 vf1 = *(const f16x8*)(VS + LSWZ(16*nt + lc, 32 + 8*lr));
        o1a[nt] = MFMA16(pa0, vf0, o1a[nt]);
        o1a[nt] = MFMA16(pa1, vf1, o1a[nt]);
      }
      __builtin_amdgcn_s_setprio(0);
    }
    // no s3: next tile writes the OTHER KB/VS buffer; R panel written next
    // tile was last read before this tile's s2.
  }
  // epilogue: reduce s per row; write fac_t (for pv2) and normalized out1
  float invs[4];
  #pragma unroll
  for (int r = 0; r < 4; r++) {
    float s = ssum[r];
    #pragma unroll
    for (int mk = 1; mk <= 8; mk <<= 1) s += __shfl_xor(s, mk);
    invs[r] = 1.f / s;
    int il = 16*w + 4*lr + r;
    float mf = m_run[r];
    #pragma unroll
    for (int jtb = 0; jtb < 2; jtb++) {
      int jt = jtb * 16 + lc;
      float mv = (jtb == 0) ? mreg0[r] : mreg1[r];
      float fv = exp2f(mv - mf) * invs[r];
      fac_t[((size_t)z * 32 + jt) * NSEQ + i0 + il] = fv;
    }
  }
  #pragma unroll
  for (int nt = 0; nt < 4; nt++)
    #pragma unroll
    for (int r = 0; r < 4; r++) {
      int rw = i0 + 16*w + 4*lr + r;
      o1acc[((size_t)b * NSEQ + rw) * 512 + h * 64 + 16*nt + lc] = (f16)(o1a[nt][r] * invs[r]);
    }
}

// ---------------- pv2: out2[j,d] = sum_i attnT[j,i]*fac_t[jt,i]*v1[i,d] ----
// A-fragments straight from global attnT (no LDS); Vs = v1t rows scaled by
// fac_t at staging (swizzled b128, conflict-free), double-buffered ->
// 1 barrier per k-step.
__global__ __launch_bounds__(256) void pv2_k(const f16* __restrict__ attnT,
    const f16* __restrict__ v1t, const float* __restrict__ fac_t,
    f16* __restrict__ oacc, int bh0)
{
  __shared__ char vsm[16384];   // 2 x [64] swizzled rows: [d][k=i]
  int z = blockIdx.y, bh = bh0 + z, b = bh >> 3, h = bh & 7;
  int r0 = blockIdx.x * 64;     // j-block == jt index
  int tid = threadIdx.x, w = tid >> 6, lane = tid & 63;
  int lr = lane >> 4, lc = lane & 15;
  int row = tid >> 2, cv = (tid & 3) * 16;
  const f16* vp = v1t + ((size_t)bh * 64 + row) * NSEQ + cv;
  const float* fp = fac_t + ((size_t)z * 32 + blockIdx.x) * NSEQ + cv;
  const f16* ap = attnT + ((size_t)z * NSEQ + r0 + 16*w + lc) * NSEQ + 8*lr;
  f32x4 acc[4] = {};
  for (int k0 = 0; k0 < NSEQ; k0 += 64) {
    char* vb = vsm + (((k0 >> 6) & 1) << 13);
    f16x8 v0 = *(const f16x8*)(vp + k0);
    f16x8 v1 = *(const f16x8*)(vp + k0 + 8);
    float4 f0 = *(const float4*)(fp + k0),     f1 = *(const float4*)(fp + k0 + 4);
    float4 f2 = *(const float4*)(fp + k0 + 8), f3 = *(const float4*)(fp + k0 + 12);
    *(f16x8*)(vb + LSWZ(row, cv))     = scale8(v0, f0, f1);
    *(f16x8*)(vb + LSWZ(row, cv + 8)) = scale8(v1, f2, f3);
    __syncthreads();   // vb visible; also separates k0-2's reads from k0's writes
    f16x8 a0 = *(const f16x8*)(ap + k0);
    f16x8 a1 = *(const f16x8*)(ap + k0 + 32);
    #pragma unroll
    for (int nt = 0; nt < 4; nt++) {
      acc[nt] = MFMA16(a0, *(const f16x8*)(vb + LSWZ(16*nt + lc, 8*lr)), acc[nt]);
      acc[nt] = MFMA16(a1, *(const f16x8*)(vb + LSWZ(16*nt + lc, 32 + 8*lr)), acc[nt]);
    }
  }
  #pragma unroll
  for (int nt = 0; nt < 4; nt++)
    #pragma unroll
    for (int r = 0; r < 4; r++) {
      int rw = r0 + 16*w + 4*lr + r;
      oacc[((size_t)b * NSEQ + rw) * 512 + h * 64 + 16*nt + lc] = (f16)acc[nt][r];
    }
}

extern "C" void kernel_launch(void* const* d_in, const int* in_sizes, int n_in,
                              void* d_out, int out_size, void* d_ws, size_t ws_size,
                              hipStream_t stream) {
  const float* x1   = (const float*)d_in[0];
  const float* x2   = (const float*)d_in[1];
  const float* Wq   = (const float*)d_in[2];
  const float* Wk   = (const float*)d_in[3];
  const float* Wv1  = (const float*)d_in[4];
  const float* Wv2  = (const float*)d_in[5];
  const float* Wrel = (const float*)d_in[6];
  const float* rpb  = (const float*)d_in[7];
  const float* Wo1  = (const float*)d_in[8];
  const float* bo1  = (const float*)d_in[9];
  const float* Wo2  = (const float*)d_in[10];
  const float* bo2  = (const float*)d_in[11];
  float* out = (float*)d_out;

  char* base = (char*)d_ws;
  size_t off = 0;
  auto alloc = [&](size_t bytes) -> void* {
    void* p = base + off; off += (bytes + 255) & ~(size_t)255; return p;
  };
  float* pos   = (float*)alloc((size_t)NPOS * 192 * 4);
  f16*   relq  = (f16*)  alloc((size_t)NH * NPOS * 64 * 2);
  f16*   qh    = (f16*)  alloc((size_t)16 * NSEQ * 64 * 2);
  f16*   kbh   = (f16*)  alloc((size_t)16 * NSEQ * 64 * 2);
  f16*   v1t   = (f16*)  alloc((size_t)16 * 64 * NSEQ * 2);
  f16*   v2t   = (f16*)  alloc((size_t)16 * 64 * NSEQ * 2);
  f16*   o1acc = (f16*)  alloc((size_t)2 * NSEQ * 512 * 2);
  f16*   o2acc = (f16*)  alloc((size_t)2 * NSEQ * 512 * 2);
  float* fac_t = (float*)alloc((size_t)16 * 32 * NSEQ * 4);
  size_t baseB = off;

  int chunk = 1;
  for (int c = 16; c >= 1; c >>= 1) {
    size_t needB = baseB + (size_t)c * NSEQ * NSEQ * 2;
    if (needB <= ws_size) { chunk = c; break; }
  }
  f16* attnT = (f16*)(base + baseB);

  pos_embed_k<<<(NPOS + 7) / 8, 256, 0, stream>>>(pos);
  relq_k<<<dim3(8, 64), 256, 0, stream>>>(pos, Wrel, relq);
  projx_k<1024, false><<<dim3(16, 64), 256, 0, stream>>>(x1, Wq, Wv1, qh, v1t, nullptr);
  projx_k<512,  true ><<<dim3(16, 64), 256, 0, stream>>>(x2, Wk, Wv2, kbh, v2t, rpb);

  for (int bh0 = 0; bh0 < 16; bh0 += chunk) {
    attn_k<<<dim3(32, chunk), 256, 0, stream>>>(qh, kbh, relq, v2t, attnT, fac_t, o1acc, bh0);
    pv2_k<<<dim3(32, chunk), 256, 0, stream>>>(attnT, v1t, fac_t, o2acc, bh0);
  }

  outproj_k<<<dim3(16, 128), 256, 0, stream>>>(o1acc, o2acc, Wo1, Wo2, bo1, bo2, out);
}

// Round 17
// 265.159 us; speedup vs baseline: 1.2035x; 1.1314x over previous
//
#include <hip/hip_runtime.h>
#include <math.h>

#define NSEQ 2048
#define NPOS 4095   // 2*NSEQ-1
#define NH   8
#define LOG2E 1.4426950408889634f

typedef _Float16 f16;
typedef f16 f16x8 __attribute__((ext_vector_type(8)));
typedef f16 f16x4 __attribute__((ext_vector_type(4)));
typedef float f32x4 __attribute__((ext_vector_type(4)));

#define MFMA16(a,b,c) __builtin_amdgcn_mfma_f32_16x16x32_f16(a,b,c,0,0,0)
// swizzled LDS byte offset: row stride 128B, 16B-granule XOR on (row&7)
#define LSWZ(row, col) (((row) << 7) + ((((col) << 1)) ^ (((row) & 7) << 4)))

__device__ __forceinline__ f16x8 cvt8(float4 a, float4 b) {
  f16x8 r = {(f16)a.x, (f16)a.y, (f16)a.z, (f16)a.w,
             (f16)b.x, (f16)b.y, (f16)b.z, (f16)b.w};
  return r;
}
__device__ __forceinline__ f16x8 scale8(f16x8 v, float4 a, float4 b) {
  f16x8 r;
  r[0] = (f16)((float)v[0] * a.x); r[1] = (f16)((float)v[1] * a.y);
  r[2] = (f16)((float)v[2] * a.z); r[3] = (f16)((float)v[3] * a.w);
  r[4] = (f16)((float)v[4] * b.x); r[5] = (f16)((float)v[5] * b.y);
  r[6] = (f16)((float)v[6] * b.z); r[7] = (f16)((float)v[7] * b.w);
  return r;
}

// ---------------- positional embedding pos[NPOS][192], one lane per (t,f) ----
__global__ __launch_bounds__(256) void pos_embed_k(float* __restrict__ pos) {
  int t = blockIdx.x * 8 + (threadIdx.x >> 5);
  int f = threadIdx.x & 31;
  if (t >= NPOS) return;
  float dist = (float)(t - (NSEQ - 1));
  float ad = fabsf(dist);
  float sgn = (dist > 0.f) ? 1.f : ((dist < 0.f) ? -1.f : 0.f);
  double mean = 64.0 * (double)(f + 1);       // linspace(64,2048,32)
  double conc = (mean / 32.0) * (mean / 32.0);
  double rate = mean / 1024.0;
  double p = 0.0;
  if (ad > 0.f) {
    double lu = (conc - 1.0) * log((double)ad) - rate * (double)ad;
    double ln = lgamma(conc) - conc * log(rate);
    p = exp(lu - ln);
  }
  float pf = (float)p + 1e-8f;
  float gmax = pf;
  #pragma unroll
  for (int mk = 1; mk <= 16; mk <<= 1) gmax = fmaxf(gmax, __shfl_xor(gmax, mk));
  float fg = pf / gmax;
  float hl = exp2f(3.f + 8.f * (float)f * (1.f / 31.f));
  float fe = exp2f(-ad / hl);
  float cw = exp2f((float)(f + 1)) - 1.f;
  float fc = (cw > ad) ? 1.f : 0.f;
  float* row = pos + (size_t)t * 192;
  row[f]       = fe;       row[32 + f]  = fc;       row[64 + f]  = fg;
  row[96 + f]  = sgn * fe; row[128 + f] = sgn * fc; row[160 + f] = sgn * fg;
}

// ---------------- relq = pos @ Wrel -> f16 [h][NPOS][64], scaled by log2e ---
__global__ __launch_bounds__(256) void relq_k(
    const float* __restrict__ A, const float* __restrict__ W, f16* __restrict__ relq)
{
  __shared__ f16 As[64][56];
  __shared__ f16 Bs[64][56];
  int tid = threadIdx.x, w = tid >> 6, lane = tid & 63, lr = lane >> 4, lc = lane & 15;
  int m0 = blockIdx.y * 64, n0 = blockIdx.x * 64;
  int ar = tid >> 2, ac = (tid & 3) * 8;
  int bk = tid >> 3, bn = (tid & 7) * 8;
  f32x4 acc[4] = {};
  for (int k0 = 0; k0 < 192; k0 += 32) {
    float4 a0 = make_float4(0.f,0.f,0.f,0.f), a1 = a0;
    if (m0 + ar < NPOS) {
      const float* ap = &A[(size_t)(m0 + ar) * 192 + k0 + ac];
      a0 = *(const float4*)ap; a1 = *(const float4*)(ap + 4);
    }
    *(f16x8*)&As[ar][ac] = cvt8(a0, a1);
    const float* bp = &W[(size_t)(k0 + bk) * 512 + n0 + bn];
    float4 b0 = *(const float4*)bp, b1 = *(const float4*)(bp + 4);
    f16 bv[8] = {(f16)b0.x,(f16)b0.y,(f16)b0.z,(f16)b0.w,(f16)b1.x,(f16)b1.y,(f16)b1.z,(f16)b1.w};
    #pragma unroll
    for (int tt = 0; tt < 8; tt++) { int t = (tt + bk) & 7; Bs[bn + t][bk] = bv[t]; }
    __syncthreads();
    f16x8 af = *(const f16x8*)&As[16*w + lc][8*lr];
    #pragma unroll
    for (int nt = 0; nt < 4; nt++) {
      f16x8 bf = *(const f16x8*)&Bs[16*nt + lc][8*lr];
      acc[nt] = MFMA16(af, bf, acc[nt]);
    }
    __syncthreads();
  }
  #pragma unroll
  for (int nt = 0; nt < 4; nt++)
    #pragma unroll
    for (int r = 0; r < 4; r++) {
      int m = m0 + 16*w + 4*lr + r;
      if (m >= NPOS) continue;
      int nn = n0 + 16*nt + lc;
      relq[((size_t)(nn >> 6) * NPOS + m) * 64 + (nn & 63)] = (f16)(acc[nt][r] * LOG2E);
    }
}

// ---------------- input projections, 128x64 tile: A[4096,KD] x (W1|W2) -----
// Wave w computes m-subtiles {2w,2w+1} x 4 n-subtiles = 8 MFMA per k-step.
// first half (n0g<512) -> O1 head-split; SC1? (*0.125+rpb) : (*log2e)
// second half -> O2t TRANSPOSED [bh][d][2048]
template<int KD, bool SC1>
__global__ __launch_bounds__(256) void projx_k(
    const float* __restrict__ A, const float* __restrict__ W1, const float* __restrict__ W2,
    f16* __restrict__ O1, f16* __restrict__ O2t, const float* __restrict__ rpb)
{
  __shared__ f16 As[128][40];
  __shared__ f16 Bs[64][40];
  int tid = threadIdx.x, w = tid >> 6, lane = tid & 63, lr = lane >> 4, lc = lane & 15;
  int m0 = blockIdx.y * 128, n0g = blockIdx.x * 64;
  bool first = (n0g < 512);
  const float* W = first ? W1 : W2;
  int n0 = n0g & 511;
  int ar = tid >> 1, ac = (tid & 1) * 16;
  int bk = tid >> 3, bn = (tid & 7) * 8;
  f32x4 acc[2][4] = {};
  for (int k0 = 0; k0 < KD; k0 += 32) {
    const float* ap = &A[(size_t)(m0 + ar) * KD + k0 + ac];
    *(f16x8*)&As[ar][ac]     = cvt8(*(const float4*)ap, *(const float4*)(ap + 4));
    *(f16x8*)&As[ar][ac + 8] = cvt8(*(const float4*)(ap + 8), *(const float4*)(ap + 12));
    const float* bp = &W[(size_t)(k0 + bk) * 512 + n0 + bn];
    float4 b0 = *(const float4*)bp, b1 = *(const float4*)(bp + 4);
    f16 bv[8] = {(f16)b0.x,(f16)b0.y,(f16)b0.z,(f16)b0.w,(f16)b1.x,(f16)b1.y,(f16)b1.z,(f16)b1.w};
    #pragma unroll
    for (int tt = 0; tt < 8; tt++) { int t = (tt + bk) & 7; Bs[bn + t][bk] = bv[t]; }
    __syncthreads();
    f16x8 af[2], bf[4];
    #pragma unroll
    for (int x = 0; x < 2; x++) af[x] = *(const f16x8*)&As[16*(2*w + x) + lc][8*lr];
    #pragma unroll
    for (int y = 0; y < 4; y++) bf[y] = *(const f16x8*)&Bs[16*y + lc][8*lr];
    #pragma unroll
    for (int x = 0; x < 2; x++)
      #pragma unroll
      for (int y = 0; y < 4; y++) acc[x][y] = MFMA16(af[x], bf[y], acc[x][y]);
    __syncthreads();
  }
  if (first) {
    #pragma unroll
    for (int x = 0; x < 2; x++)
      #pragma unroll
      for (int y = 0; y < 4; y++)
        #pragma unroll
        for (int r = 0; r < 4; r++) {
          int m = m0 + 16*(2*w + x) + 4*lr + r;
          int nn = n0 + 16*y + lc;
          float vv = acc[x][y][r];
          if (SC1) vv = vv * 0.125f + rpb[nn];
          else     vv = vv * LOG2E;
          O1[(((size_t)((m >> 11) * NH + (nn >> 6))) * NSEQ + (m & (NSEQ - 1))) * 64 + (nn & 63)] = (f16)vv;
        }
  } else {
    #pragma unroll
    for (int x = 0; x < 2; x++) {
      int mb = m0 + 16*(2*w + x) + 4*lr;
      #pragma unroll
      for (int y = 0; y < 4; y++) {
        int nn = n0 + 16*y + lc;
        f16x4 pk = {(f16)acc[x][y][0], (f16)acc[x][y][1], (f16)acc[x][y][2], (f16)acc[x][y][3]};
        *(f16x4*)&O2t[(((size_t)((mb >> 11) * NH + (nn >> 6))) * 64 + (nn & 63)) * NSEQ + (mb & (NSEQ - 1))] = pk;
      }
    }
  }
}

// ---------------- fused output projections, 128x64 tile ----------------
__global__ __launch_bounds__(256) void outproj_k(
    const f16* __restrict__ o1, const f16* __restrict__ o2,
    const float* __restrict__ Wo1, const float* __restrict__ Wo2,
    const float* __restrict__ bo1, const float* __restrict__ bo2,
    float* __restrict__ out)
{
  __shared__ f16 As[128][40];
  __shared__ f16 Bs[64][40];
  int by = blockIdx.y;
  bool first = (by < 32);
  const f16* A = first ? o1 : o2;
  const float* W = first ? Wo1 : Wo2;
  const float* bias = first ? bo1 : bo2;
  float* O = out + (first ? 0 : (size_t)4096 * 1024);
  int tid = threadIdx.x, w = tid >> 6, lane = tid & 63, lr = lane >> 4, lc = lane & 15;
  int m0 = (by & 31) * 128, n0 = blockIdx.x * 64;
  int ar = tid >> 1, ac = (tid & 1) * 16;
  int bk = tid >> 3, bn = (tid & 7) * 8;
  f32x4 acc[2][4] = {};
  for (int k0 = 0; k0 < 512; k0 += 32) {
    const f16* ap = &A[(size_t)(m0 + ar) * 512 + k0 + ac];
    *(f16x8*)&As[ar][ac]     = *(const f16x8*)ap;
    *(f16x8*)&As[ar][ac + 8] = *(const f16x8*)(ap + 8);
    const float* bp = &W[(size_t)(k0 + bk) * 1024 + n0 + bn];
    float4 b0 = *(const float4*)bp, b1 = *(const float4*)(bp + 4);
    f16 bv[8] = {(f16)b0.x,(f16)b0.y,(f16)b0.z,(f16)b0.w,(f16)b1.x,(f16)b1.y,(f16)b1.z,(f16)b1.w};
    #pragma unroll
    for (int tt = 0; tt < 8; tt++) { int t = (tt + bk) & 7; Bs[bn + t][bk] = bv[t]; }
    __syncthreads();
    f16x8 af[2], bf[4];
    #pragma unroll
    for (int x = 0; x < 2; x++) af[x] = *(const f16x8*)&As[16*(2*w + x) + lc][8*lr];
    #pragma unroll
    for (int y = 0; y < 4; y++) bf[y] = *(const f16x8*)&Bs[16*y + lc][8*lr];
    #pragma unroll
    for (int x = 0; x < 2; x++)
      #pragma unroll
      for (int y = 0; y < 4; y++) acc[x][y] = MFMA16(af[x], bf[y], acc[x][y]);
    __syncthreads();
  }
  #pragma unroll
  for (int x = 0; x < 2; x++)
    #pragma unroll
    for (int y = 0; y < 4; y++)
      #pragma unroll
      for (int r = 0; r < 4; r++) {
        int m = m0 + 16*(2*w + x) + 4*lr + r;
        int n = n0 + 16*y + lc;
        O[(size_t)m * 1024 + n] = acc[x][y][r] + bias[n];
      }
}

// ---------------- fused logits + online softmax + out1 PV ----------------
// Round-16 proven structure: 4 waves, double-buffered KB/VS, dedicated PW,
// 2 barriers/tile. LDS 65536 B: QG(Q+G2)@0, KB0@8192, KB1@16384, VS0@24576,
// VS1@32768, R0@40960, R1@49152, PW@57344 (per-wave 2048B).
__global__ __launch_bounds__(256) void attn_k(
    const f16* __restrict__ q, const f16* __restrict__ kb,
    const f16* __restrict__ relq, const f16* __restrict__ v2t,
    f16* __restrict__ attnT, float* __restrict__ fac_t,
    f16* __restrict__ o1acc, int bh0)
{
  __shared__ char smem[65536];
  char* QG  = smem;
  char* KB0 = smem + 8192;
  char* KB1 = smem + 16384;
  char* VS0 = smem + 24576;
  char* VS1 = smem + 32768;
  char* R0  = smem + 40960;
  char* R1  = smem + 49152;
  int z = blockIdx.y, bh = bh0 + z, b = bh >> 3, h = bh & 7;
  int i0 = blockIdx.x * 64;
  int tid = threadIdx.x, w = tid >> 6, lane = tid & 63;
  int lr = lane >> 4, lc = lane & 15;
  char* PW = smem + 57344 + w * 2048;   // per-wave [16] swizzled rows
  int base0 = i0 + 1984;                // (NSEQ-1) + i0 - 63
  int row = tid >> 2, c0 = (tid & 3) * 16;

  {
    const f16* qp = q + ((size_t)bh * NSEQ + i0 + row) * 64 + c0;
    *(f16x8*)(QG + LSWZ(row, c0))     = *(const f16x8*)qp;
    *(f16x8*)(QG + LSWZ(row, c0 + 8)) = *(const f16x8*)(qp + 8);
    // prologue: panel -1 -> R1 (jt=0 uses RsA=R0, RsB=R1)
    const f16* rp = relq + ((size_t)h * NPOS + base0 + 64 + row) * 64 + c0;
    *(f16x8*)(R1 + LSWZ(row, c0))     = *(const f16x8*)rp;
    *(f16x8*)(R1 + LSWZ(row, c0 + 8)) = *(const f16x8*)(rp + 8);
  }
  __syncthreads();
  f16x8 qa0 = *(const f16x8*)(QG + LSWZ(16*w + lc, 8*lr));
  f16x8 qa1 = *(const f16x8*)(QG + LSWZ(16*w + lc, 32 + 8*lr));

  // tile-0 prefetch registers
  const f16* kpb  = kb  + ((size_t)bh * NSEQ + row) * 64 + c0;
  const f16* vpb  = v2t + ((size_t)bh * 64 + row) * NSEQ + c0;
  const f16* rpb0 = relq + ((size_t)h * NPOS + base0 + row) * 64 + c0;
  f16x8 skb0 = *(const f16x8*)kpb,  skb1 = *(const f16x8*)(kpb + 8);
  f16x8 sv0  = *(const f16x8*)vpb,  sv1  = *(const f16x8*)(vpb + 8);
  f16x8 sr0  = *(const f16x8*)rpb0, sr1  = *(const f16x8*)(rpb0 + 8);

  float m_run[4], ssum[4];
  float mreg0[4] = {}, mreg1[4] = {};
  f32x4 o1a[4] = {};
  #pragma unroll
  for (int r = 0; r < 4; r++) { m_run[r] = -1e30f; ssum[r] = 0.f; }

  for (int jt = 0; jt < 32; jt++) {
    int j0 = jt * 64;
    char* KB  = (jt & 1) ? KB1 : KB0;
    char* VS  = (jt & 1) ? VS1 : VS0;
    char* RsA = (jt & 1) ? R1 : R0;   // panel jt: n in [0,64)
    char* RsB = (jt & 1) ? R0 : R1;   // panel jt-1: n in [64,128)
    *(f16x8*)(KB + LSWZ(row, c0))      = skb0;  *(f16x8*)(KB + LSWZ(row, c0 + 8))  = skb1;
    *(f16x8*)(VS + LSWZ(row, c0))      = sv0;   *(f16x8*)(VS + LSWZ(row, c0 + 8))  = sv1;
    *(f16x8*)(RsA + LSWZ(row, c0))     = sr0;   *(f16x8*)(RsA + LSWZ(row, c0 + 8)) = sr1;
    __syncthreads();   // s1: staging visible; prev tile's G2 reads all done
    f32x4 cacc[4];
    f16x8 ka0 = {}, ka1 = {};
    __builtin_amdgcn_s_setprio(1);
    #pragma unroll
    for (int y = 0; y < 4; y++) {
      f16x8 b0 = *(const f16x8*)(KB + LSWZ(16*y + lc, 8*lr));
      f16x8 b1 = *(const f16x8*)(KB + LSWZ(16*y + lc, 32 + 8*lr));
      f32x4 t = {};
      t = MFMA16(qa0, b0, t);
      t = MFMA16(qa1, b1, t);
      cacc[y] = t;
      if (y == w) { ka0 = b0; ka1 = b1; }
    }
    __builtin_amdgcn_s_setprio(0);
    // G blocks: only g in [3-w, 7-w] contribute
    #pragma unroll
    for (int gg = 0; gg < 5; gg++) {
      int g = 3 - w + gg;
      char* Rg = (g < 4) ? RsA : RsB;
      int grow = 16 * (g & 3) + lc;
      f32x4 ga = {};
      ga = MFMA16(ka0, *(const f16x8*)(Rg + LSWZ(grow, 8*lr)), ga);
      ga = MFMA16(ka1, *(const f16x8*)(Rg + LSWZ(grow, 32 + 8*lr)), ga);
      int jj = 16*w + 4*lr;
      #pragma unroll
      for (int r = 0; r < 4; r++) {
        int ii = 16*g + lc + jj + r - 63;   // i = n + j - 63
        if ((unsigned)ii < 64u) *(f16*)(QG + LSWZ(jj + r, ii)) = (f16)ga[r];
      }
    }
    // prefetch next tile into registers (hides under softmax+PV)
    {
      int jn = (jt < 31) ? jt + 1 : 31;
      const f16* kpn = kb  + ((size_t)bh * NSEQ + jn * 64 + row) * 64 + c0;
      const f16* vpn = v2t + ((size_t)bh * 64 + row) * NSEQ + jn * 64 + c0;
      const f16* rpn = relq + ((size_t)h * NPOS + base0 - 64 * jn + row) * 64 + c0;
      skb0 = *(const f16x8*)kpn;  skb1 = *(const f16x8*)(kpn + 8);
      sv0  = *(const f16x8*)vpn;  sv1  = *(const f16x8*)(vpn + 8);
      sr0  = *(const f16x8*)rpn;  sr1  = *(const f16x8*)(rpn + 8);
    }
    __syncthreads();   // s2: G2 scatter complete; KB frag reads done
    float l[4][4];
    #pragma unroll
    for (int y = 0; y < 4; y++) {
      f16x4 gv = *(const f16x4*)(QG + LSWZ(16*y + lc, 16*w + 4*lr));
      #pragma unroll
      for (int r = 0; r < 4; r++) l[y][r] = cacc[y][r] + (float)gv[r];
    }
    float pvr[4][4];   // [r][y]
    #pragma unroll
    for (int r = 0; r < 4; r++) {
      float tm = fmaxf(fmaxf(l[0][r], l[1][r]), fmaxf(l[2][r], l[3][r]));
      #pragma unroll
      for (int mk = 1; mk <= 8; mk <<= 1) tm = fmaxf(tm, __shfl_xor(tm, mk));
      if (tm > m_run[r]) {
        float sc = exp2f(m_run[r] - tm);
        ssum[r] *= sc;
        #pragma unroll
        for (int nt = 0; nt < 4; nt++) o1a[nt][r] *= sc;
        m_run[r] = tm;
      }
      float mnew = m_run[r];
      float ps = 0.f;
      #pragma unroll
      for (int y = 0; y < 4; y++) {
        float p = exp2f(l[y][r] - mnew);
        ps += p;
        pvr[r][y] = p;
        *(f16*)(PW + LSWZ(4*lr + r, 16*y + lc)) = (f16)p;
      }
      ssum[r] += ps;
      // capture running max per tile in registers: lane lc owns jt=lc, 16+lc
      if (jt < 16) { if (lc == jt) mreg0[r] = mnew; }
      else         { if (lc == jt - 16) mreg1[r] = mnew; }
    }
    // transposed P store, direct from registers: attnT[j][i]
    #pragma unroll
    for (int y = 0; y < 4; y++) {
      f16x4 pk = {(f16)pvr[0][y], (f16)pvr[1][y], (f16)pvr[2][y], (f16)pvr[3][y]};
      *(f16x4*)&attnT[((size_t)z * NSEQ + j0 + 16*y + lc) * NSEQ + i0 + 16*w + 4*lr] = pk;
    }
    // out1 PV (PW per-wave, lgkmcnt-ordered)
    {
      f16x8 pa0 = *(const f16x8*)(PW + LSWZ(lc, 8*lr));
      f16x8 pa1 = *(const f16x8*)(PW + LSWZ(lc, 32 + 8*lr));
      __builtin_amdgcn_s_setprio(1);
      #pragma unroll
      for (int nt = 0; nt < 4; nt++) {
        f16x8 vf0 = *(const f16x8*)(VS + LSWZ(16*nt + lc, 8*lr));
        f16x8 vf1 = *(const f16x8*)(VS + LSWZ(16*nt + lc, 32 + 8*lr));
        o1a[nt] = MFMA16(pa0, vf0, o1a[nt]);
        o1a[nt] = MFMA16(pa1, vf1, o1a[nt]);
      }
      __builtin_amdgcn_s_setprio(0);
    }
    // no s3: next tile writes the OTHER KB/VS buffer
  }
  // epilogue: reduce s per row; write fac_t (for pv2) and normalized out1
  float invs[4];
  #pragma unroll
  for (int r = 0; r < 4; r++) {
    float s = ssum[r];
    #pragma unroll
    for (int mk = 1; mk <= 8; mk <<= 1) s += __shfl_xor(s, mk);
    invs[r] = 1.f / s;
    int il = 16*w + 4*lr + r;
    float mf = m_run[r];
    #pragma unroll
    for (int jtb = 0; jtb < 2; jtb++) {
      int jt = jtb * 16 + lc;
      float mv = (jtb == 0) ? mreg0[r] : mreg1[r];
      float fv = exp2f(mv - mf) * invs[r];
      fac_t[((size_t)z * 32 + jt) * NSEQ + i0 + il] = fv;
    }
  }
  #pragma unroll
  for (int nt = 0; nt < 4; nt++)
    #pragma unroll
    for (int r = 0; r < 4; r++) {
      int rw = i0 + 16*w + 4*lr + r;
      o1acc[((size_t)b * NSEQ + rw) * 512 + h * 64 + 16*nt + lc] = (f16)(o1a[nt][r] * invs[r]);
    }
}

// ---------------- pv2: out2[j,d] = sum_i attnT[j,i]*fac_t[jt,i]*v1[i,d] ----
// A-fragments straight from global attnT (no LDS); Vs = v1t rows scaled by
// fac_t at staging (swizzled b128, conflict-free), double-buffered ->
// 1 barrier per k-step.
__global__ __launch_bounds__(256) void pv2_k(const f16* __restrict__ attnT,
    const f16* __restrict__ v1t, const float* __restrict__ fac_t,
    f16* __restrict__ oacc, int bh0)
{
  __shared__ char vsm[16384];   // 2 x [64] swizzled rows: [d][k=i]
  int z = blockIdx.y, bh = bh0 + z, b = bh >> 3, h = bh & 7;
  int r0 = blockIdx.x * 64;     // j-block == jt index
  int tid = threadIdx.x, w = tid >> 6, lane = tid & 63;
  int lr = lane >> 4, lc = lane & 15;
  int row = tid >> 2, cv = (tid & 3) * 16;
  const f16* vp = v1t + ((size_t)bh * 64 + row) * NSEQ + cv;
  const float* fp = fac_t + ((size_t)z * 32 + blockIdx.x) * NSEQ + cv;
  const f16* ap = attnT + ((size_t)z * NSEQ + r0 + 16*w + lc) * NSEQ + 8*lr;
  f32x4 acc[4] = {};
  for (int k0 = 0; k0 < NSEQ; k0 += 64) {
    char* vb = vsm + (((k0 >> 6) & 1) << 13);
    f16x8 v0 = *(const f16x8*)(vp + k0);
    f16x8 v1 = *(const f16x8*)(vp + k0 + 8);
    float4 f0 = *(const float4*)(fp + k0),     f1 = *(const float4*)(fp + k0 + 4);
    float4 f2 = *(const float4*)(fp + k0 + 8), f3 = *(const float4*)(fp + k0 + 12);
    *(f16x8*)(vb + LSWZ(row, cv))     = scale8(v0, f0, f1);
    *(f16x8*)(vb + LSWZ(row, cv + 8)) = scale8(v1, f2, f3);
    __syncthreads();
    f16x8 a0 = *(const f16x8*)(ap + k0);
    f16x8 a1 = *(const f16x8*)(ap + k0 + 32);
    #pragma unroll
    for (int nt = 0; nt < 4; nt++) {
      acc[nt] = MFMA16(a0, *(const f16x8*)(vb + LSWZ(16*nt + lc, 8*lr)), acc[nt]);
      acc[nt] = MFMA16(a1, *(const f16x8*)(vb + LSWZ(16*nt + lc, 32 + 8*lr)), acc[nt]);
    }
  }
  #pragma unroll
  for (int nt = 0; nt < 4; nt++)
    #pragma unroll
    for (int r = 0; r < 4; r++) {
      int rw = r0 + 16*w + 4*lr + r;
      oacc[((size_t)b * NSEQ + rw) * 512 + h * 64 + 16*nt + lc] = (f16)acc[nt][r];
    }
}

extern "C" void kernel_launch(void* const* d_in, const int* in_sizes, int n_in,
                              void* d_out, int out_size, void* d_ws, size_t ws_size,
                              hipStream_t stream) {
  const float* x1   = (const float*)d_in[0];
  const float* x2   = (const float*)d_in[1];
  const float* Wq   = (const float*)d_in[2];
  const float* Wk   = (const float*)d_in[3];
  const float* Wv1  = (const float*)d_in[4];
  const float* Wv2  = (const float*)d_in[5];
  const float* Wrel = (const float*)d_in[6];
  const float* rpb  = (const float*)d_in[7];
  const float* Wo1  = (const float*)d_in[8];
  const float* bo1  = (const float*)d_in[9];
  const float* Wo2  = (const float*)d_in[10];
  const float* bo2  = (const float*)d_in[11];
  float* out = (float*)d_out;

  char* base = (char*)d_ws;
  size_t off = 0;
  auto alloc = [&](size_t bytes) -> void* {
    void* p = base + off; off += (bytes + 255) & ~(size_t)255; return p;
  };
  float* pos   = (float*)alloc((size_t)NPOS * 192 * 4);
  f16*   relq  = (f16*)  alloc((size_t)NH * NPOS * 64 * 2);
  f16*   qh    = (f16*)  alloc((size_t)16 * NSEQ * 64 * 2);
  f16*   kbh   = (f16*)  alloc((size_t)16 * NSEQ * 64 * 2);
  f16*   v1t   = (f16*)  alloc((size_t)16 * 64 * NSEQ * 2);
  f16*   v2t   = (f16*)  alloc((size_t)16 * 64 * NSEQ * 2);
  f16*   o1acc = (f16*)  alloc((size_t)2 * NSEQ * 512 * 2);
  f16*   o2acc = (f16*)  alloc((size_t)2 * NSEQ * 512 * 2);
  float* fac_t = (float*)alloc((size_t)16 * 32 * NSEQ * 4);
  size_t baseB = off;

  int chunk = 1;
  for (int c = 16; c >= 1; c >>= 1) {
    size_t needB = baseB + (size_t)c * NSEQ * NSEQ * 2;
    if (needB <= ws_size) { chunk = c; break; }
  }
  f16* attnT = (f16*)(base + baseB);

  pos_embed_k<<<(NPOS + 7) / 8, 256, 0, stream>>>(pos);
  relq_k<<<dim3(8, 64), 256, 0, stream>>>(pos, Wrel, relq);
  projx_k<1024, false><<<dim3(16, 32), 256, 0, stream>>>(x1, Wq, Wv1, qh, v1t, nullptr);
  projx_k<512,  true ><<<dim3(16, 32), 256, 0, stream>>>(x2, Wk, Wv2, kbh, v2t, rpb);

  for (int bh0 = 0; bh0 < 16; bh0 += chunk) {
    attn_k<<<dim3(32, chunk), 256, 0, stream>>>(qh, kbh, relq, v2t, attnT, fac_t, o1acc, bh0);
    pv2_k<<<dim3(32, chunk), 256, 0, stream>>>(attnT, v1t, fac_t, o2acc, bh0);
  }

  outproj_k<<<dim3(16, 64), 256, 0, stream>>>(o1acc, o2acc, Wo1, Wo2, bo1, bo2, out);
}

// Round 18
// 264.006 us; speedup vs baseline: 1.2088x; 1.0044x over previous
//
#include <hip/hip_runtime.h>
#include <math.h>

#define NSEQ 2048
#define NPOS 4095   // 2*NSEQ-1
#define NH   8
#define LOG2E 1.4426950408889634f

typedef _Float16 f16;
typedef f16 f16x8 __attribute__((ext_vector_type(8)));
typedef f16 f16x4 __attribute__((ext_vector_type(4)));
typedef float f32x4 __attribute__((ext_vector_type(4)));

#define MFMA16(a,b,c) __builtin_amdgcn_mfma_f32_16x16x32_f16(a,b,c,0,0,0)
// swizzled LDS byte offset: row stride 128B, 16B-granule XOR on (row&7)
#define LSWZ(row, col) (((row) << 7) + ((((col) << 1)) ^ (((row) & 7) << 4)))

__device__ __forceinline__ f16x8 cvt8(float4 a, float4 b) {
  f16x8 r = {(f16)a.x, (f16)a.y, (f16)a.z, (f16)a.w,
             (f16)b.x, (f16)b.y, (f16)b.z, (f16)b.w};
  return r;
}
__device__ __forceinline__ f16x8 scale8(f16x8 v, float4 a, float4 b) {
  f16x8 r;
  r[0] = (f16)((float)v[0] * a.x); r[1] = (f16)((float)v[1] * a.y);
  r[2] = (f16)((float)v[2] * a.z); r[3] = (f16)((float)v[3] * a.w);
  r[4] = (f16)((float)v[4] * b.x); r[5] = (f16)((float)v[5] * b.y);
  r[6] = (f16)((float)v[6] * b.z); r[7] = (f16)((float)v[7] * b.w);
  return r;
}

// ---------------- positional embedding pos[NPOS][192], one lane per (t,f) ----
__global__ __launch_bounds__(256) void pos_embed_k(float* __restrict__ pos) {
  int t = blockIdx.x * 8 + (threadIdx.x >> 5);
  int f = threadIdx.x & 31;
  if (t >= NPOS) return;
  float dist = (float)(t - (NSEQ - 1));
  float ad = fabsf(dist);
  float sgn = (dist > 0.f) ? 1.f : ((dist < 0.f) ? -1.f : 0.f);
  double mean = 64.0 * (double)(f + 1);       // linspace(64,2048,32)
  double conc = (mean / 32.0) * (mean / 32.0);
  double rate = mean / 1024.0;
  double p = 0.0;
  if (ad > 0.f) {
    double lu = (conc - 1.0) * log((double)ad) - rate * (double)ad;
    double ln = lgamma(conc) - conc * log(rate);
    p = exp(lu - ln);
  }
  float pf = (float)p + 1e-8f;
  float gmax = pf;
  #pragma unroll
  for (int mk = 1; mk <= 16; mk <<= 1) gmax = fmaxf(gmax, __shfl_xor(gmax, mk));
  float fg = pf / gmax;
  float hl = exp2f(3.f + 8.f * (float)f * (1.f / 31.f));
  float fe = exp2f(-ad / hl);
  float cw = exp2f((float)(f + 1)) - 1.f;
  float fc = (cw > ad) ? 1.f : 0.f;
  float* row = pos + (size_t)t * 192;
  row[f]       = fe;       row[32 + f]  = fc;       row[64 + f]  = fg;
  row[96 + f]  = sgn * fe; row[128 + f] = sgn * fc; row[160 + f] = sgn * fg;
}

// ---------------- relq = pos @ Wrel -> f16 [h][NPOS][64], 128x64 tile -------
__global__ __launch_bounds__(256) void relq_k(
    const float* __restrict__ A, const float* __restrict__ W, f16* __restrict__ relq)
{
  __shared__ f16 As[128][40];
  __shared__ f16 Bs[64][40];
  int tid = threadIdx.x, w = tid >> 6, lane = tid & 63, lr = lane >> 4, lc = lane & 15;
  int m0 = blockIdx.y * 128, n0 = blockIdx.x * 64;
  int ar = tid >> 1, ac = (tid & 1) * 16;
  int bk = tid >> 3, bn = (tid & 7) * 8;
  f32x4 acc[2][4] = {};
  for (int k0 = 0; k0 < 192; k0 += 32) {
    float4 a0 = make_float4(0.f,0.f,0.f,0.f), a1 = a0, a2 = a0, a3 = a0;
    if (m0 + ar < NPOS) {
      const float* ap = &A[(size_t)(m0 + ar) * 192 + k0 + ac];
      a0 = *(const float4*)ap;       a1 = *(const float4*)(ap + 4);
      a2 = *(const float4*)(ap + 8); a3 = *(const float4*)(ap + 12);
    }
    *(f16x8*)&As[ar][ac]     = cvt8(a0, a1);
    *(f16x8*)&As[ar][ac + 8] = cvt8(a2, a3);
    const float* bp = &W[(size_t)(k0 + bk) * 512 + n0 + bn];
    float4 b0 = *(const float4*)bp, b1 = *(const float4*)(bp + 4);
    f16 bv[8] = {(f16)b0.x,(f16)b0.y,(f16)b0.z,(f16)b0.w,(f16)b1.x,(f16)b1.y,(f16)b1.z,(f16)b1.w};
    #pragma unroll
    for (int tt = 0; tt < 8; tt++) { int t = (tt + bk) & 7; Bs[bn + t][bk] = bv[t]; }
    __syncthreads();
    f16x8 af[2], bf[4];
    #pragma unroll
    for (int x = 0; x < 2; x++) af[x] = *(const f16x8*)&As[16*(2*w + x) + lc][8*lr];
    #pragma unroll
    for (int y = 0; y < 4; y++) bf[y] = *(const f16x8*)&Bs[16*y + lc][8*lr];
    #pragma unroll
    for (int x = 0; x < 2; x++)
      #pragma unroll
      for (int y = 0; y < 4; y++) acc[x][y] = MFMA16(af[x], bf[y], acc[x][y]);
    __syncthreads();
  }
  #pragma unroll
  for (int x = 0; x < 2; x++)
    #pragma unroll
    for (int y = 0; y < 4; y++)
      #pragma unroll
      for (int r = 0; r < 4; r++) {
        int m = m0 + 16*(2*w + x) + 4*lr + r;
        if (m >= NPOS) continue;
        int nn = n0 + 16*y + lc;
        relq[((size_t)(nn >> 6) * NPOS + m) * 64 + (nn & 63)] = (f16)(acc[x][y][r] * LOG2E);
      }
}

// ---------------- input projections, 128x64 tile: A[4096,KD] x (W1|W2) -----
template<int KD, bool SC1>
__global__ __launch_bounds__(256) void projx_k(
    const float* __restrict__ A, const float* __restrict__ W1, const float* __restrict__ W2,
    f16* __restrict__ O1, f16* __restrict__ O2t, const float* __restrict__ rpb)
{
  __shared__ f16 As[128][40];
  __shared__ f16 Bs[64][40];
  int tid = threadIdx.x, w = tid >> 6, lane = tid & 63, lr = lane >> 4, lc = lane & 15;
  int m0 = blockIdx.y * 128, n0g = blockIdx.x * 64;
  bool first = (n0g < 512);
  const float* W = first ? W1 : W2;
  int n0 = n0g & 511;
  int ar = tid >> 1, ac = (tid & 1) * 16;
  int bk = tid >> 3, bn = (tid & 7) * 8;
  f32x4 acc[2][4] = {};
  for (int k0 = 0; k0 < KD; k0 += 32) {
    const float* ap = &A[(size_t)(m0 + ar) * KD + k0 + ac];
    *(f16x8*)&As[ar][ac]     = cvt8(*(const float4*)ap, *(const float4*)(ap + 4));
    *(f16x8*)&As[ar][ac + 8] = cvt8(*(const float4*)(ap + 8), *(const float4*)(ap + 12));
    const float* bp = &W[(size_t)(k0 + bk) * 512 + n0 + bn];
    float4 b0 = *(const float4*)bp, b1 = *(const float4*)(bp + 4);
    f16 bv[8] = {(f16)b0.x,(f16)b0.y,(f16)b0.z,(f16)b0.w,(f16)b1.x,(f16)b1.y,(f16)b1.z,(f16)b1.w};
    #pragma unroll
    for (int tt = 0; tt < 8; tt++) { int t = (tt + bk) & 7; Bs[bn + t][bk] = bv[t]; }
    __syncthreads();
    f16x8 af[2], bf[4];
    #pragma unroll
    for (int x = 0; x < 2; x++) af[x] = *(const f16x8*)&As[16*(2*w + x) + lc][8*lr];
    #pragma unroll
    for (int y = 0; y < 4; y++) bf[y] = *(const f16x8*)&Bs[16*y + lc][8*lr];
    #pragma unroll
    for (int x = 0; x < 2; x++)
      #pragma unroll
      for (int y = 0; y < 4; y++) acc[x][y] = MFMA16(af[x], bf[y], acc[x][y]);
    __syncthreads();
  }
  if (first) {
    #pragma unroll
    for (int x = 0; x < 2; x++)
      #pragma unroll
      for (int y = 0; y < 4; y++)
        #pragma unroll
        for (int r = 0; r < 4; r++) {
          int m = m0 + 16*(2*w + x) + 4*lr + r;
          int nn = n0 + 16*y + lc;
          float vv = acc[x][y][r];
          if (SC1) vv = vv * 0.125f + rpb[nn];
          else     vv = vv * LOG2E;
          O1[(((size_t)((m >> 11) * NH + (nn >> 6))) * NSEQ + (m & (NSEQ - 1))) * 64 + (nn & 63)] = (f16)vv;
        }
  } else {
    #pragma unroll
    for (int x = 0; x < 2; x++) {
      int mb = m0 + 16*(2*w + x) + 4*lr;
      #pragma unroll
      for (int y = 0; y < 4; y++) {
        int nn = n0 + 16*y + lc;
        f16x4 pk = {(f16)acc[x][y][0], (f16)acc[x][y][1], (f16)acc[x][y][2], (f16)acc[x][y][3]};
        *(f16x4*)&O2t[(((size_t)((mb >> 11) * NH + (nn >> 6))) * 64 + (nn & 63)) * NSEQ + (mb & (NSEQ - 1))] = pk;
      }
    }
  }
}

// ---------------- fused output projections, 128x64 tile ----------------
__global__ __launch_bounds__(256) void outproj_k(
    const f16* __restrict__ o1, const f16* __restrict__ o2,
    const float* __restrict__ Wo1, const float* __restrict__ Wo2,
    const float* __restrict__ bo1, const float* __restrict__ bo2,
    float* __restrict__ out)
{
  __shared__ f16 As[128][40];
  __shared__ f16 Bs[64][40];
  int by = blockIdx.y;
  bool first = (by < 32);
  const f16* A = first ? o1 : o2;
  const float* W = first ? Wo1 : Wo2;
  const float* bias = first ? bo1 : bo2;
  float* O = out + (first ? 0 : (size_t)4096 * 1024);
  int tid = threadIdx.x, w = tid >> 6, lane = tid & 63, lr = lane >> 4, lc = lane & 15;
  int m0 = (by & 31) * 128, n0 = blockIdx.x * 64;
  int ar = tid >> 1, ac = (tid & 1) * 16;
  int bk = tid >> 3, bn = (tid & 7) * 8;
  f32x4 acc[2][4] = {};
  for (int k0 = 0; k0 < 512; k0 += 32) {
    const f16* ap = &A[(size_t)(m0 + ar) * 512 + k0 + ac];
    *(f16x8*)&As[ar][ac]     = *(const f16x8*)ap;
    *(f16x8*)&As[ar][ac + 8] = *(const f16x8*)(ap + 8);
    const float* bp = &W[(size_t)(k0 + bk) * 1024 + n0 + bn];
    float4 b0 = *(const float4*)bp, b1 = *(const float4*)(bp + 4);
    f16 bv[8] = {(f16)b0.x,(f16)b0.y,(f16)b0.z,(f16)b0.w,(f16)b1.x,(f16)b1.y,(f16)b1.z,(f16)b1.w};
    #pragma unroll
    for (int tt = 0; tt < 8; tt++) { int t = (tt + bk) & 7; Bs[bn + t][bk] = bv[t]; }
    __syncthreads();
    f16x8 af[2], bf[4];
    #pragma unroll
    for (int x = 0; x < 2; x++) af[x] = *(const f16x8*)&As[16*(2*w + x) + lc][8*lr];
    #pragma unroll
    for (int y = 0; y < 4; y++) bf[y] = *(const f16x8*)&Bs[16*y + lc][8*lr];
    #pragma unroll
    for (int x = 0; x < 2; x++)
      #pragma unroll
      for (int y = 0; y < 4; y++) acc[x][y] = MFMA16(af[x], bf[y], acc[x][y]);
    __syncthreads();
  }
  #pragma unroll
  for (int x = 0; x < 2; x++)
    #pragma unroll
    for (int y = 0; y < 4; y++)
      #pragma unroll
      for (int r = 0; r < 4; r++) {
        int m = m0 + 16*(2*w + x) + 4*lr + r;
        int n = n0 + 16*y + lc;
        O[(size_t)m * 1024 + n] = acc[x][y][r] + bias[n];
      }
}

// ---------------- fused logits + online softmax + out1 PV ----------------
// Round-16 proven structure; grid SWAPPED to (z, i0) so all 32 i-blocks of a
// bh land on one XCD (flat%8 = z%8) -> per-z kb/v2t/relq streams become
// XCD-L2-resident. Micro: ph[] f16 converted once (PW + attnT pack), prefetch
// pointers incremented instead of recomputed.
// LDS 65536 B: QG(Q+G2)@0, KB0@8192, KB1@16384, VS0@24576, VS1@32768,
// R0@40960, R1@49152, PW@57344 (per-wave 2048B).
__global__ __launch_bounds__(256) void attn_k(
    const f16* __restrict__ q, const f16* __restrict__ kb,
    const f16* __restrict__ relq, const f16* __restrict__ v2t,
    f16* __restrict__ attnT, float* __restrict__ fac_t,
    f16* __restrict__ o1acc, int bh0)
{
  __shared__ char smem[65536];
  char* QG  = smem;
  char* KB0 = smem + 8192;
  char* KB1 = smem + 16384;
  char* VS0 = smem + 24576;
  char* VS1 = smem + 32768;
  char* R0  = smem + 40960;
  char* R1  = smem + 49152;
  int z = blockIdx.x, bh = bh0 + z, b = bh >> 3, h = bh & 7;
  int i0 = blockIdx.y * 64;
  int tid = threadIdx.x, w = tid >> 6, lane = tid & 63;
  int lr = lane >> 4, lc = lane & 15;
  char* PW = smem + 57344 + w * 2048;   // per-wave [16] swizzled rows
  int base0 = i0 + 1984;                // (NSEQ-1) + i0 - 63
  int row = tid >> 2, c0 = (tid & 3) * 16;

  {
    const f16* qp = q + ((size_t)bh * NSEQ + i0 + row) * 64 + c0;
    *(f16x8*)(QG + LSWZ(row, c0))     = *(const f16x8*)qp;
    *(f16x8*)(QG + LSWZ(row, c0 + 8)) = *(const f16x8*)(qp + 8);
    // prologue: panel -1 -> R1 (jt=0 uses RsA=R0, RsB=R1)
    const f16* rp = relq + ((size_t)h * NPOS + base0 + 64 + row) * 64 + c0;
    *(f16x8*)(R1 + LSWZ(row, c0))     = *(const f16x8*)rp;
    *(f16x8*)(R1 + LSWZ(row, c0 + 8)) = *(const f16x8*)(rp + 8);
  }
  __syncthreads();
  f16x8 qa0 = *(const f16x8*)(QG + LSWZ(16*w + lc, 8*lr));
  f16x8 qa1 = *(const f16x8*)(QG + LSWZ(16*w + lc, 32 + 8*lr));

  // tile-0 prefetch pointers (incremented each tile)
  const f16* kp_pf = kb  + ((size_t)bh * NSEQ + row) * 64 + c0;
  const f16* vp_pf = v2t + ((size_t)bh * 64 + row) * NSEQ + c0;
  const f16* rp_pf = relq + ((size_t)h * NPOS + base0 + row) * 64 + c0;
  f16x8 skb0 = *(const f16x8*)kp_pf,  skb1 = *(const f16x8*)(kp_pf + 8);
  f16x8 sv0  = *(const f16x8*)vp_pf,  sv1  = *(const f16x8*)(vp_pf + 8);
  f16x8 sr0  = *(const f16x8*)rp_pf,  sr1  = *(const f16x8*)(rp_pf + 8);

  float m_run[4], ssum[4];
  float mreg0[4] = {}, mreg1[4] = {};
  f32x4 o1a[4] = {};
  #pragma unroll
  for (int r = 0; r < 4; r++) { m_run[r] = -1e30f; ssum[r] = 0.f; }

  for (int jt = 0; jt < 32; jt++) {
    int j0 = jt * 64;
    char* KB  = (jt & 1) ? KB1 : KB0;
    char* VS  = (jt & 1) ? VS1 : VS0;
    char* RsA = (jt & 1) ? R1 : R0;   // panel jt: n in [0,64)
    char* RsB = (jt & 1) ? R0 : R1;   // panel jt-1: n in [64,128)
    *(f16x8*)(KB + LSWZ(row, c0))      = skb0;  *(f16x8*)(KB + LSWZ(row, c0 + 8))  = skb1;
    *(f16x8*)(VS + LSWZ(row, c0))      = sv0;   *(f16x8*)(VS + LSWZ(row, c0 + 8))  = sv1;
    *(f16x8*)(RsA + LSWZ(row, c0))     = sr0;   *(f16x8*)(RsA + LSWZ(row, c0 + 8)) = sr1;
    __syncthreads();   // s1: staging visible; prev tile's G2 reads all done
    f32x4 cacc[4];
    f16x8 ka0 = {}, ka1 = {};
    __builtin_amdgcn_s_setprio(1);
    #pragma unroll
    for (int y = 0; y < 4; y++) {
      f16x8 b0 = *(const f16x8*)(KB + LSWZ(16*y + lc, 8*lr));
      f16x8 b1 = *(const f16x8*)(KB + LSWZ(16*y + lc, 32 + 8*lr));
      f32x4 t = {};
      t = MFMA16(qa0, b0, t);
      t = MFMA16(qa1, b1, t);
      cacc[y] = t;
      if (y == w) { ka0 = b0; ka1 = b1; }
    }
    __builtin_amdgcn_s_setprio(0);
    // G blocks: only g in [3-w, 7-w] contribute
    #pragma unroll
    for (int gg = 0; gg < 5; gg++) {
      int g = 3 - w + gg;
      char* Rg = (g < 4) ? RsA : RsB;
      int grow = 16 * (g & 3) + lc;
      f32x4 ga = {};
      ga = MFMA16(ka0, *(const f16x8*)(Rg + LSWZ(grow, 8*lr)), ga);
      ga = MFMA16(ka1, *(const f16x8*)(Rg + LSWZ(grow, 32 + 8*lr)), ga);
      int jj = 16*w + 4*lr;
      #pragma unroll
      for (int r = 0; r < 4; r++) {
        int ii = 16*g + lc + jj + r - 63;   // i = n + j - 63
        if ((unsigned)ii < 64u) *(f16*)(QG + LSWZ(jj + r, ii)) = (f16)ga[r];
      }
    }
    // prefetch next tile into registers (hides under softmax+PV)
    {
      if (jt < 31) { kp_pf += 64 * 64; vp_pf += 64; rp_pf -= 64 * 64; }
      skb0 = *(const f16x8*)kp_pf;  skb1 = *(const f16x8*)(kp_pf + 8);
      sv0  = *(const f16x8*)vp_pf;  sv1  = *(const f16x8*)(vp_pf + 8);
      sr0  = *(const f16x8*)rp_pf;  sr1  = *(const f16x8*)(rp_pf + 8);
    }
    __syncthreads();   // s2: G2 scatter complete; KB frag reads done
    float l[4][4];
    #pragma unroll
    for (int y = 0; y < 4; y++) {
      f16x4 gv = *(const f16x4*)(QG + LSWZ(16*y + lc, 16*w + 4*lr));
      #pragma unroll
      for (int r = 0; r < 4; r++) l[y][r] = cacc[y][r] + (float)gv[r];
    }
    f16 ph[4][4];   // [r][y], converted once
    #pragma unroll
    for (int r = 0; r < 4; r++) {
      float tm = fmaxf(fmaxf(l[0][r], l[1][r]), fmaxf(l[2][r], l[3][r]));
      #pragma unroll
      for (int mk = 1; mk <= 8; mk <<= 1) tm = fmaxf(tm, __shfl_xor(tm, mk));
      if (tm > m_run[r]) {
        float sc = exp2f(m_run[r] - tm);
        ssum[r] *= sc;
        #pragma unroll
        for (int nt = 0; nt < 4; nt++) o1a[nt][r] *= sc;
        m_run[r] = tm;
      }
      float mnew = m_run[r];
      float ps = 0.f;
      #pragma unroll
      for (int y = 0; y < 4; y++) {
        float p = exp2f(l[y][r] - mnew);
        ps += p;
        ph[r][y] = (f16)p;
        *(f16*)(PW + LSWZ(4*lr + r, 16*y + lc)) = ph[r][y];
      }
      ssum[r] += ps;
      // capture running max per tile in registers: lane lc owns jt=lc, 16+lc
      if (jt < 16) { if (lc == jt) mreg0[r] = mnew; }
      else         { if (lc == jt - 16) mreg1[r] = mnew; }
    }
    // transposed P store, direct from registers: attnT[j][i]
    #pragma unroll
    for (int y = 0; y < 4; y++) {
      f16x4 pk = {ph[0][y], ph[1][y], ph[2][y], ph[3][y]};
      *(f16x4*)&attnT[((size_t)z * NSEQ + j0 + 16*y + lc) * NSEQ + i0 + 16*w + 4*lr] = pk;
    }
    // out1 PV (PW per-wave, lgkmcnt-ordered)
    {
      f16x8 pa0 = *(const f16x8*)(PW + LSWZ(lc, 8*lr));
      f16x8 pa1 = *(const f16x8*)(PW + LSWZ(lc, 32 + 8*lr));
      __builtin_amdgcn_s_setprio(1);
      #pragma unroll
      for (int nt = 0; nt < 4; nt++) {
        f16x8 vf0 = *(const f16x8*)(VS + LSWZ(16*nt + lc, 8*lr));
        f16x8 vf1 = *(const f16x8*)(VS + LSWZ(16*nt + lc, 32 + 8*lr));
        o1a[nt] = MFMA16(pa0, vf0, o1a[nt]);
        o1a[nt] = MFMA16(pa1, vf1, o1a[nt]);
      }
      __builtin_amdgcn_s_setprio(0);
    }
    // no s3: next tile writes the OTHER KB/VS buffer
  }
  // epilogue: reduce s per row; write fac_t (for pv2) and normalized out1
  float invs[4];
  #pragma unroll
  for (int r = 0; r < 4; r++) {
    float s = ssum[r];
    #pragma unroll
    for (int mk = 1; mk <= 8; mk <<= 1) s += __shfl_xor(s, mk);
    invs[r] = 1.f / s;
    int il = 16*w + 4*lr + r;
    float mf = m_run[r];
    #pragma unroll
    for (int jtb = 0; jtb < 2; jtb++) {
      int jt = jtb * 16 + lc;
      float mv = (jtb == 0) ? mreg0[r] : mreg1[r];
      float fv = exp2f(mv - mf) * invs[r];
      fac_t[((size_t)z * 32 + jt) * NSEQ + i0 + il] = fv;
    }
  }
  #pragma unroll
  for (int nt = 0; nt < 4; nt++)
    #pragma unroll
    for (int r = 0; r < 4; r++) {
      int rw = i0 + 16*w + 4*lr + r;
      o1acc[((size_t)b * NSEQ + rw) * 512 + h * 64 + 16*nt + lc] = (f16)(o1a[nt][r] * invs[r]);
    }
}

// ---------------- pv2: out2[j,d] = sum_i attnT[j,i]*fac_t[jt,i]*v1[i,d] ----
// Grid swapped to (z, jt) for XCD locality (same-z blocks share v1t/attnT/fac).
__global__ __launch_bounds__(256) void pv2_k(const f16* __restrict__ attnT,
    const f16* __restrict__ v1t, const float* __restrict__ fac_t,
    f16* __restrict__ oacc, int bh0)
{
  __shared__ char vsm[16384];   // 2 x [64] swizzled rows: [d][k=i]
  int z = blockIdx.x, bh = bh0 + z, b = bh >> 3, h = bh & 7;
  int r0 = blockIdx.y * 64;     // j-block == jt index
  int tid = threadIdx.x, w = tid >> 6, lane = tid & 63;
  int lr = lane >> 4, lc = lane & 15;
  int row = tid >> 2, cv = (tid & 3) * 16;
  const f16* vp = v1t + ((size_t)bh * 64 + row) * NSEQ + cv;
  const float* fp = fac_t + ((size_t)z * 32 + blockIdx.y) * NSEQ + cv;
  const f16* ap = attnT + ((size_t)z * NSEQ + r0 + 16*w + lc) * NSEQ + 8*lr;
  f32x4 acc[4] = {};
  for (int k0 = 0; k0 < NSEQ; k0 += 64) {
    char* vb = vsm + (((k0 >> 6) & 1) << 13);
    f16x8 v0 = *(const f16x8*)(vp + k0);
    f16x8 v1 = *(const f16x8*)(vp + k0 + 8);
    float4 f0 = *(const float4*)(fp + k0),     f1 = *(const float4*)(fp + k0 + 4);
    float4 f2 = *(const float4*)(fp + k0 + 8), f3 = *(const float4*)(fp + k0 + 12);
    *(f16x8*)(vb + LSWZ(row, cv))     = scale8(v0, f0, f1);
    *(f16x8*)(vb + LSWZ(row, cv + 8)) = scale8(v1, f2, f3);
    __syncthreads();
    f16x8 a0 = *(const f16x8*)(ap + k0);
    f16x8 a1 = *(const f16x8*)(ap + k0 + 32);
    #pragma unroll
    for (int nt = 0; nt < 4; nt++) {
      acc[nt] = MFMA16(a0, *(const f16x8*)(vb + LSWZ(16*nt + lc, 8*lr)), acc[nt]);
      acc[nt] = MFMA16(a1, *(const f16x8*)(vb + LSWZ(16*nt + lc, 32 + 8*lr)), acc[nt]);
    }
  }
  #pragma unroll
  for (int nt = 0; nt < 4; nt++)
    #pragma unroll
    for (int r = 0; r < 4; r++) {
      int rw = r0 + 16*w + 4*lr + r;
      oacc[((size_t)b * NSEQ + rw) * 512 + h * 64 + 16*nt + lc] = (f16)acc[nt][r];
    }
}

extern "C" void kernel_launch(void* const* d_in, const int* in_sizes, int n_in,
                              void* d_out, int out_size, void* d_ws, size_t ws_size,
                              hipStream_t stream) {
  const float* x1   = (const float*)d_in[0];
  const float* x2   = (const float*)d_in[1];
  const float* Wq   = (const float*)d_in[2];
  const float* Wk   = (const float*)d_in[3];
  const float* Wv1  = (const float*)d_in[4];
  const float* Wv2  = (const float*)d_in[5];
  const float* Wrel = (const float*)d_in[6];
  const float* rpb  = (const float*)d_in[7];
  const float* Wo1  = (const float*)d_in[8];
  const float* bo1  = (const float*)d_in[9];
  const float* Wo2  = (const float*)d_in[10];
  const float* bo2  = (const float*)d_in[11];
  float* out = (float*)d_out;

  char* base = (char*)d_ws;
  size_t off = 0;
  auto alloc = [&](size_t bytes) -> void* {
    void* p = base + off; off += (bytes + 255) & ~(size_t)255; return p;
  };
  float* pos   = (float*)alloc((size_t)NPOS * 192 * 4);
  f16*   relq  = (f16*)  alloc((size_t)NH * NPOS * 64 * 2);
  f16*   qh    = (f16*)  alloc((size_t)16 * NSEQ * 64 * 2);
  f16*   kbh   = (f16*)  alloc((size_t)16 * NSEQ * 64 * 2);
  f16*   v1t   = (f16*)  alloc((size_t)16 * 64 * NSEQ * 2);
  f16*   v2t   = (f16*)  alloc((size_t)16 * 64 * NSEQ * 2);
  f16*   o1acc = (f16*)  alloc((size_t)2 * NSEQ * 512 * 2);
  f16*   o2acc = (f16*)  alloc((size_t)2 * NSEQ * 512 * 2);
  float* fac_t = (float*)alloc((size_t)16 * 32 * NSEQ * 4);
  size_t baseB = off;

  int chunk = 1;
  for (int c = 16; c >= 1; c >>= 1) {
    size_t needB = baseB + (size_t)c * NSEQ * NSEQ * 2;
    if (needB <= ws_size) { chunk = c; break; }
  }
  f16* attnT = (f16*)(base + baseB);

  pos_embed_k<<<(NPOS + 7) / 8, 256, 0, stream>>>(pos);
  relq_k<<<dim3(8, 32), 256, 0, stream>>>(pos, Wrel, relq);
  projx_k<1024, false><<<dim3(16, 32), 256, 0, stream>>>(x1, Wq, Wv1, qh, v1t, nullptr);
  projx_k<512,  true ><<<dim3(16, 32), 256, 0, stream>>>(x2, Wk, Wv2, kbh, v2t, rpb);

  for (int bh0 = 0; bh0 < 16; bh0 += chunk) {
    attn_k<<<dim3(chunk, 32), 256, 0, stream>>>(qh, kbh, relq, v2t, attnT, fac_t, o1acc, bh0);
    pv2_k<<<dim3(chunk, 32), 256, 0, stream>>>(attnT, v1t, fac_t, o2acc, bh0);
  }

  outproj_k<<<dim3(16, 64), 256, 0, stream>>>(o1acc, o2acc, Wo1, Wo2, bo1, bo2, out);
}

// Round 19
// 245.928 us; speedup vs baseline: 1.2976x; 1.0735x over previous
//
#include <hip/hip_runtime.h>
#include <math.h>

#define NSEQ 2048
#define NPOS 4095   // 2*NSEQ-1
#define NH   8
#define LOG2E 1.4426950408889634f

typedef _Float16 f16;
typedef f16 f16x8 __attribute__((ext_vector_type(8)));
typedef f16 f16x4 __attribute__((ext_vector_type(4)));
typedef float f32x4 __attribute__((ext_vector_type(4)));

#define MFMA16(a,b,c) __builtin_amdgcn_mfma_f32_16x16x32_f16(a,b,c,0,0,0)
// swizzled LDS byte offset: row stride 128B, 16B-granule XOR on (row&7)
#define LSWZ(row, col) (((row) << 7) + ((((col) << 1)) ^ (((row) & 7) << 4)))

__device__ __forceinline__ f16x8 cvt8(float4 a, float4 b) {
  f16x8 r = {(f16)a.x, (f16)a.y, (f16)a.z, (f16)a.w,
             (f16)b.x, (f16)b.y, (f16)b.z, (f16)b.w};
  return r;
}
__device__ __forceinline__ f16x8 scale8(f16x8 v, float4 a, float4 b) {
  f16x8 r;
  r[0] = (f16)((float)v[0] * a.x); r[1] = (f16)((float)v[1] * a.y);
  r[2] = (f16)((float)v[2] * a.z); r[3] = (f16)((float)v[3] * a.w);
  r[4] = (f16)((float)v[4] * b.x); r[5] = (f16)((float)v[5] * b.y);
  r[6] = (f16)((float)v[6] * b.z); r[7] = (f16)((float)v[7] * b.w);
  return r;
}

// ---------------- positional embedding pos[NPOS][192], one lane per (t,f) ----
__global__ __launch_bounds__(256) void pos_embed_k(float* __restrict__ pos) {
  int t = blockIdx.x * 8 + (threadIdx.x >> 5);
  int f = threadIdx.x & 31;
  if (t >= NPOS) return;
  float dist = (float)(t - (NSEQ - 1));
  float ad = fabsf(dist);
  float sgn = (dist > 0.f) ? 1.f : ((dist < 0.f) ? -1.f : 0.f);
  double mean = 64.0 * (double)(f + 1);       // linspace(64,2048,32)
  double conc = (mean / 32.0) * (mean / 32.0);
  double rate = mean / 1024.0;
  double p = 0.0;
  if (ad > 0.f) {
    double lu = (conc - 1.0) * log((double)ad) - rate * (double)ad;
    double ln = lgamma(conc) - conc * log(rate);
    p = exp(lu - ln);
  }
  float pf = (float)p + 1e-8f;
  float gmax = pf;
  #pragma unroll
  for (int mk = 1; mk <= 16; mk <<= 1) gmax = fmaxf(gmax, __shfl_xor(gmax, mk));
  float fg = pf / gmax;
  float hl = exp2f(3.f + 8.f * (float)f * (1.f / 31.f));
  float fe = exp2f(-ad / hl);
  float cw = exp2f((float)(f + 1)) - 1.f;
  float fc = (cw > ad) ? 1.f : 0.f;
  float* row = pos + (size_t)t * 192;
  row[f]       = fe;       row[32 + f]  = fc;       row[64 + f]  = fg;
  row[96 + f]  = sgn * fe; row[128 + f] = sgn * fc; row[160 + f] = sgn * fg;
}

// ---------------- weight transpose+cvt: f32 [K][N] -> f16 [N][K] (scaled) ----
// One dispatch; blockIdx.z selects the weight. Scales folded: Wq,Wrel *LOG2E,
// Wk *0.125.
__global__ __launch_bounds__(256) void wtrans_k(
    const float* __restrict__ w0, const float* __restrict__ w1,
    const float* __restrict__ w2, const float* __restrict__ w3,
    const float* __restrict__ w4, const float* __restrict__ w5,
    const float* __restrict__ w6,
    f16* __restrict__ o0, f16* __restrict__ o1, f16* __restrict__ o2,
    f16* __restrict__ o3, f16* __restrict__ o4, f16* __restrict__ o5,
    f16* __restrict__ o6)
{
  __shared__ float tile[64][65];
  int zi = blockIdx.z;
  const float* in; f16* out; int K, N; float sc;
  switch (zi) {
    case 0: in = w0; out = o0; K = 1024; N = 512;  sc = LOG2E; break;  // Wq
    case 1: in = w1; out = o1; K = 512;  N = 512;  sc = 0.125f; break; // Wk
    case 2: in = w2; out = o2; K = 1024; N = 512;  sc = 1.f; break;    // Wv1
    case 3: in = w3; out = o3; K = 512;  N = 512;  sc = 1.f; break;    // Wv2
    case 4: in = w4; out = o4; K = 192;  N = 512;  sc = LOG2E; break;  // Wrel
    case 5: in = w5; out = o5; K = 512;  N = 1024; sc = 1.f; break;    // Wo1
    default: in = w6; out = o6; K = 512; N = 1024; sc = 1.f; break;    // Wo2
  }
  int nb = blockIdx.x * 64, kb = blockIdx.y * 64;
  if (nb >= N || kb >= K) return;
  int tx = threadIdx.x & 63, ty = threadIdx.x >> 6;
  #pragma unroll
  for (int u = 0; u < 16; u++) {
    int k = ty + 4 * u;
    tile[k][tx] = in[(size_t)(kb + k) * N + nb + tx];
  }
  __syncthreads();
  #pragma unroll
  for (int u = 0; u < 16; u++) {
    int n = ty + 4 * u;
    out[(size_t)(nb + n) * K + kb + tx] = (f16)(tile[tx][n] * sc);
  }
}

// ---------------- relq = pos @ Wrelt -> f16 [h][NPOS][64], 128x64 tile ------
__global__ __launch_bounds__(256) void relq_k(
    const float* __restrict__ A, const f16* __restrict__ Wt, f16* __restrict__ relq)
{
  __shared__ f16 As[128][40];
  __shared__ f16 Bs[64][40];
  int tid = threadIdx.x, w = tid >> 6, lane = tid & 63, lr = lane >> 4, lc = lane & 15;
  int m0 = blockIdx.y * 128, n0 = blockIdx.x * 64;
  int ar = tid >> 1, ac = (tid & 1) * 16;
  int bn = tid >> 2, bkk = (tid & 3) * 8;
  f32x4 acc[2][4] = {};
  for (int k0 = 0; k0 < 192; k0 += 32) {
    float4 a0 = make_float4(0.f,0.f,0.f,0.f), a1 = a0, a2 = a0, a3 = a0;
    if (m0 + ar < NPOS) {
      const float* ap = &A[(size_t)(m0 + ar) * 192 + k0 + ac];
      a0 = *(const float4*)ap;       a1 = *(const float4*)(ap + 4);
      a2 = *(const float4*)(ap + 8); a3 = *(const float4*)(ap + 12);
    }
    *(f16x8*)&As[ar][ac]     = cvt8(a0, a1);
    *(f16x8*)&As[ar][ac + 8] = cvt8(a2, a3);
    *(f16x8*)&Bs[bn][bkk] = *(const f16x8*)&Wt[(size_t)(n0 + bn) * 192 + k0 + bkk];
    __syncthreads();
    f16x8 af[2], bf[4];
    #pragma unroll
    for (int x = 0; x < 2; x++) af[x] = *(const f16x8*)&As[16*(2*w + x) + lc][8*lr];
    #pragma unroll
    for (int y = 0; y < 4; y++) bf[y] = *(const f16x8*)&Bs[16*y + lc][8*lr];
    #pragma unroll
    for (int x = 0; x < 2; x++)
      #pragma unroll
      for (int y = 0; y < 4; y++) acc[x][y] = MFMA16(af[x], bf[y], acc[x][y]);
    __syncthreads();
  }
  #pragma unroll
  for (int x = 0; x < 2; x++)
    #pragma unroll
    for (int y = 0; y < 4; y++)
      #pragma unroll
      for (int r = 0; r < 4; r++) {
        int m = m0 + 16*(2*w + x) + 4*lr + r;
        if (m >= NPOS) continue;
        int nn = n0 + 16*y + lc;
        relq[((size_t)(nn >> 6) * NPOS + m) * 64 + (nn & 63)] = (f16)acc[x][y][r];
      }
}

// ---------------- input projections, 128x64 tile: A[4096,KD] x (Wt1|Wt2) ----
// Wt pre-transposed f16 [512][KD]; scales folded (q: LOG2E, kb: 0.125).
// first half (n0g<512) -> O1 head-split (SC1 adds rpb); second -> O2t.
template<int KD, bool SC1>
__global__ __launch_bounds__(256) void projx_k(
    const float* __restrict__ A, const f16* __restrict__ Wt1, const f16* __restrict__ Wt2,
    f16* __restrict__ O1, f16* __restrict__ O2t, const float* __restrict__ rpb)
{
  __shared__ f16 As[128][40];
  __shared__ f16 Bs[64][40];
  int tid = threadIdx.x, w = tid >> 6, lane = tid & 63, lr = lane >> 4, lc = lane & 15;
  int m0 = blockIdx.y * 128, n0g = blockIdx.x * 64;
  bool first = (n0g < 512);
  const f16* Wt = first ? Wt1 : Wt2;
  int n0 = n0g & 511;
  int ar = tid >> 1, ac = (tid & 1) * 16;
  int bn = tid >> 2, bkk = (tid & 3) * 8;
  f32x4 acc[2][4] = {};
  for (int k0 = 0; k0 < KD; k0 += 32) {
    const float* ap = &A[(size_t)(m0 + ar) * KD + k0 + ac];
    *(f16x8*)&As[ar][ac]     = cvt8(*(const float4*)ap, *(const float4*)(ap + 4));
    *(f16x8*)&As[ar][ac + 8] = cvt8(*(const float4*)(ap + 8), *(const float4*)(ap + 12));
    *(f16x8*)&Bs[bn][bkk] = *(const f16x8*)&Wt[(size_t)(n0 + bn) * KD + k0 + bkk];
    __syncthreads();
    f16x8 af[2], bf[4];
    #pragma unroll
    for (int x = 0; x < 2; x++) af[x] = *(const f16x8*)&As[16*(2*w + x) + lc][8*lr];
    #pragma unroll
    for (int y = 0; y < 4; y++) bf[y] = *(const f16x8*)&Bs[16*y + lc][8*lr];
    #pragma unroll
    for (int x = 0; x < 2; x++)
      #pragma unroll
      for (int y = 0; y < 4; y++) acc[x][y] = MFMA16(af[x], bf[y], acc[x][y]);
    __syncthreads();
  }
  if (first) {
    #pragma unroll
    for (int x = 0; x < 2; x++)
      #pragma unroll
      for (int y = 0; y < 4; y++)
        #pragma unroll
        for (int r = 0; r < 4; r++) {
          int m = m0 + 16*(2*w + x) + 4*lr + r;
          int nn = n0 + 16*y + lc;
          float vv = acc[x][y][r];
          if (SC1) vv += rpb[nn];
          O1[(((size_t)((m >> 11) * NH + (nn >> 6))) * NSEQ + (m & (NSEQ - 1))) * 64 + (nn & 63)] = (f16)vv;
        }
  } else {
    #pragma unroll
    for (int x = 0; x < 2; x++) {
      int mb = m0 + 16*(2*w + x) + 4*lr;
      #pragma unroll
      for (int y = 0; y < 4; y++) {
        int nn = n0 + 16*y + lc;
        f16x4 pk = {(f16)acc[x][y][0], (f16)acc[x][y][1], (f16)acc[x][y][2], (f16)acc[x][y][3]};
        *(f16x4*)&O2t[(((size_t)((mb >> 11) * NH + (nn >> 6))) * 64 + (nn & 63)) * NSEQ + (mb & (NSEQ - 1))] = pk;
      }
    }
  }
}

// ---------------- fused output projections, 128x64 tile (Wt f16 [1024][512])-
__global__ __launch_bounds__(256) void outproj_k(
    const f16* __restrict__ o1, const f16* __restrict__ o2,
    const f16* __restrict__ Wo1t, const f16* __restrict__ Wo2t,
    const float* __restrict__ bo1, const float* __restrict__ bo2,
    float* __restrict__ out)
{
  __shared__ f16 As[128][40];
  __shared__ f16 Bs[64][40];
  int by = blockIdx.y;
  bool first = (by < 32);
  const f16* A = first ? o1 : o2;
  const f16* Wt = first ? Wo1t : Wo2t;
  const float* bias = first ? bo1 : bo2;
  float* O = out + (first ? 0 : (size_t)4096 * 1024);
  int tid = threadIdx.x, w = tid >> 6, lane = tid & 63, lr = lane >> 4, lc = lane & 15;
  int m0 = (by & 31) * 128, n0 = blockIdx.x * 64;
  int ar = tid >> 1, ac = (tid & 1) * 16;
  int bn = tid >> 2, bkk = (tid & 3) * 8;
  f32x4 acc[2][4] = {};
  for (int k0 = 0; k0 < 512; k0 += 32) {
    const f16* ap = &A[(size_t)(m0 + ar) * 512 + k0 + ac];
    *(f16x8*)&As[ar][ac]     = *(const f16x8*)ap;
    *(f16x8*)&As[ar][ac + 8] = *(const f16x8*)(ap + 8);
    *(f16x8*)&Bs[bn][bkk] = *(const f16x8*)&Wt[(size_t)(n0 + bn) * 512 + k0 + bkk];
    __syncthreads();
    f16x8 af[2], bf[4];
    #pragma unroll
    for (int x = 0; x < 2; x++) af[x] = *(const f16x8*)&As[16*(2*w + x) + lc][8*lr];
    #pragma unroll
    for (int y = 0; y < 4; y++) bf[y] = *(const f16x8*)&Bs[16*y + lc][8*lr];
    #pragma unroll
    for (int x = 0; x < 2; x++)
      #pragma unroll
      for (int y = 0; y < 4; y++) acc[x][y] = MFMA16(af[x], bf[y], acc[x][y]);
    __syncthreads();
  }
  #pragma unroll
  for (int x = 0; x < 2; x++)
    #pragma unroll
    for (int y = 0; y < 4; y++)
      #pragma unroll
      for (int r = 0; r < 4; r++) {
        int m = m0 + 16*(2*w + x) + 4*lr + r;
        int n = n0 + 16*y + lc;
        O[(size_t)m * 1024 + n] = acc[x][y][r] + bias[n];
      }
}

// ---------------- fused logits + online softmax + out1 PV ----------------
// Round-18 proven structure (unchanged): grid (z, i0) XCD-local, 2 barriers/
// tile, double-buffered KB/VS, dedicated PW, exp2-domain softmax.
// LDS 65536 B: QG(Q+G2)@0, KB0@8192, KB1@16384, VS0@24576, VS1@32768,
// R0@40960, R1@49152, PW@57344 (per-wave 2048B).
__global__ __launch_bounds__(256) void attn_k(
    const f16* __restrict__ q, const f16* __restrict__ kb,
    const f16* __restrict__ relq, const f16* __restrict__ v2t,
    f16* __restrict__ attnT, float* __restrict__ fac_t,
    f16* __restrict__ o1acc, int bh0)
{
  __shared__ char smem[65536];
  char* QG  = smem;
  char* KB0 = smem + 8192;
  char* KB1 = smem + 16384;
  char* VS0 = smem + 24576;
  char* VS1 = smem + 32768;
  char* R0  = smem + 40960;
  char* R1  = smem + 49152;
  int z = blockIdx.x, bh = bh0 + z, b = bh >> 3, h = bh & 7;
  int i0 = blockIdx.y * 64;
  int tid = threadIdx.x, w = tid >> 6, lane = tid & 63;
  int lr = lane >> 4, lc = lane & 15;
  char* PW = smem + 57344 + w * 2048;   // per-wave [16] swizzled rows
  int base0 = i0 + 1984;                // (NSEQ-1) + i0 - 63
  int row = tid >> 2, c0 = (tid & 3) * 16;

  {
    const f16* qp = q + ((size_t)bh * NSEQ + i0 + row) * 64 + c0;
    *(f16x8*)(QG + LSWZ(row, c0))     = *(const f16x8*)qp;
    *(f16x8*)(QG + LSWZ(row, c0 + 8)) = *(const f16x8*)(qp + 8);
    // prologue: panel -1 -> R1 (jt=0 uses RsA=R0, RsB=R1)
    const f16* rp = relq + ((size_t)h * NPOS + base0 + 64 + row) * 64 + c0;
    *(f16x8*)(R1 + LSWZ(row, c0))     = *(const f16x8*)rp;
    *(f16x8*)(R1 + LSWZ(row, c0 + 8)) = *(const f16x8*)(rp + 8);
  }
  __syncthreads();
  f16x8 qa0 = *(const f16x8*)(QG + LSWZ(16*w + lc, 8*lr));
  f16x8 qa1 = *(const f16x8*)(QG + LSWZ(16*w + lc, 32 + 8*lr));

  // tile-0 prefetch pointers (incremented each tile)
  const f16* kp_pf = kb  + ((size_t)bh * NSEQ + row) * 64 + c0;
  const f16* vp_pf = v2t + ((size_t)bh * 64 + row) * NSEQ + c0;
  const f16* rp_pf = relq + ((size_t)h * NPOS + base0 + row) * 64 + c0;
  f16x8 skb0 = *(const f16x8*)kp_pf,  skb1 = *(const f16x8*)(kp_pf + 8);
  f16x8 sv0  = *(const f16x8*)vp_pf,  sv1  = *(const f16x8*)(vp_pf + 8);
  f16x8 sr0  = *(const f16x8*)rp_pf,  sr1  = *(const f16x8*)(rp_pf + 8);

  float m_run[4], ssum[4];
  float mreg0[4] = {}, mreg1[4] = {};
  f32x4 o1a[4] = {};
  #pragma unroll
  for (int r = 0; r < 4; r++) { m_run[r] = -1e30f; ssum[r] = 0.f; }

  for (int jt = 0; jt < 32; jt++) {
    int j0 = jt * 64;
    char* KB  = (jt & 1) ? KB1 : KB0;
    char* VS  = (jt & 1) ? VS1 : VS0;
    char* RsA = (jt & 1) ? R1 : R0;   // panel jt: n in [0,64)
    char* RsB = (jt & 1) ? R0 : R1;   // panel jt-1: n in [64,128)
    *(f16x8*)(KB + LSWZ(row, c0))      = skb0;  *(f16x8*)(KB + LSWZ(row, c0 + 8))  = skb1;
    *(f16x8*)(VS + LSWZ(row, c0))      = sv0;   *(f16x8*)(VS + LSWZ(row, c0 + 8))  = sv1;
    *(f16x8*)(RsA + LSWZ(row, c0))     = sr0;   *(f16x8*)(RsA + LSWZ(row, c0 + 8)) = sr1;
    __syncthreads();   // s1: staging visible; prev tile's G2 reads all done
    f32x4 cacc[4];
    f16x8 ka0 = {}, ka1 = {};
    __builtin_amdgcn_s_setprio(1);
    #pragma unroll
    for (int y = 0; y < 4; y++) {
      f16x8 b0 = *(const f16x8*)(KB + LSWZ(16*y + lc, 8*lr));
      f16x8 b1 = *(const f16x8*)(KB + LSWZ(16*y + lc, 32 + 8*lr));
      f32x4 t = {};
      t = MFMA16(qa0, b0, t);
      t = MFMA16(qa1, b1, t);
      cacc[y] = t;
      if (y == w) { ka0 = b0; ka1 = b1; }
    }
    __builtin_amdgcn_s_setprio(0);
    // G blocks: only g in [3-w, 7-w] contribute
    #pragma unroll
    for (int gg = 0; gg < 5; gg++) {
      int g = 3 - w + gg;
      char* Rg = (g < 4) ? RsA : RsB;
      int grow = 16 * (g & 3) + lc;
      f32x4 ga = {};
      ga = MFMA16(ka0, *(const f16x8*)(Rg + LSWZ(grow, 8*lr)), ga);
      ga = MFMA16(ka1, *(const f16x8*)(Rg + LSWZ(grow, 32 + 8*lr)), ga);
      int jj = 16*w + 4*lr;
      #pragma unroll
      for (int r = 0; r < 4; r++) {
        int ii = 16*g + lc + jj + r - 63;   // i = n + j - 63
        if ((unsigned)ii < 64u) *(f16*)(QG + LSWZ(jj + r, ii)) = (f16)ga[r];
      }
    }
    // prefetch next tile into registers (hides under softmax+PV)
    {
      if (jt < 31) { kp_pf += 64 * 64; vp_pf += 64; rp_pf -= 64 * 64; }
      skb0 = *(const f16x8*)kp_pf;  skb1 = *(const f16x8*)(kp_pf + 8);
      sv0  = *(const f16x8*)vp_pf;  sv1  = *(const f16x8*)(vp_pf + 8);
      sr0  = *(const f16x8*)rp_pf;  sr1  = *(const f16x8*)(rp_pf + 8);
    }
    __syncthreads();   // s2: G2 scatter complete; KB frag reads done
    float l[4][4];
    #pragma unroll
    for (int y = 0; y < 4; y++) {
      f16x4 gv = *(const f16x4*)(QG + LSWZ(16*y + lc, 16*w + 4*lr));
      #pragma unroll
      for (int r = 0; r < 4; r++) l[y][r] = cacc[y][r] + (float)gv[r];
    }
    f16 ph[4][4];   // [r][y], converted once
    #pragma unroll
    for (int r = 0; r < 4; r++) {
      float tm = fmaxf(fmaxf(l[0][r], l[1][r]), fmaxf(l[2][r], l[3][r]));
      #pragma unroll
      for (int mk = 1; mk <= 8; mk <<= 1) tm = fmaxf(tm, __shfl_xor(tm, mk));
      if (tm > m_run[r]) {
        float sc = exp2f(m_run[r] - tm);
        ssum[r] *= sc;
        #pragma unroll
        for (int nt = 0; nt < 4; nt++) o1a[nt][r] *= sc;
        m_run[r] = tm;
      }
      float mnew = m_run[r];
      float ps = 0.f;
      #pragma unroll
      for (int y = 0; y < 4; y++) {
        float p = exp2f(l[y][r] - mnew);
        ps += p;
        ph[r][y] = (f16)p;
        *(f16*)(PW + LSWZ(4*lr + r, 16*y + lc)) = ph[r][y];
      }
      ssum[r] += ps;
      // capture running max per tile in registers: lane lc owns jt=lc, 16+lc
      if (jt < 16) { if (lc == jt) mreg0[r] = mnew; }
      else         { if (lc == jt - 16) mreg1[r] = mnew; }
    }
    // transposed P store, direct from registers: attnT[j][i]
    #pragma unroll
    for (int y = 0; y < 4; y++) {
      f16x4 pk = {ph[0][y], ph[1][y], ph[2][y], ph[3][y]};
      *(f16x4*)&attnT[((size_t)z * NSEQ + j0 + 16*y + lc) * NSEQ + i0 + 16*w + 4*lr] = pk;
    }
    // out1 PV (PW per-wave, lgkmcnt-ordered)
    {
      f16x8 pa0 = *(const f16x8*)(PW + LSWZ(lc, 8*lr));
      f16x8 pa1 = *(const f16x8*)(PW + LSWZ(lc, 32 + 8*lr));
      __builtin_amdgcn_s_setprio(1);
      #pragma unroll
      for (int nt = 0; nt < 4; nt++) {
        f16x8 vf0 = *(const f16x8*)(VS + LSWZ(16*nt + lc, 8*lr));
        f16x8 vf1 = *(const f16x8*)(VS + LSWZ(16*nt + lc, 32 + 8*lr));
        o1a[nt] = MFMA16(pa0, vf0, o1a[nt]);
        o1a[nt] = MFMA16(pa1, vf1, o1a[nt]);
      }
      __builtin_amdgcn_s_setprio(0);
    }
    // no s3: next tile writes the OTHER KB/VS buffer
  }
  // epilogue: reduce s per row; write fac_t (for pv2) and normalized out1
  float invs[4];
  #pragma unroll
  for (int r = 0; r < 4; r++) {
    float s = ssum[r];
    #pragma unroll
    for (int mk = 1; mk <= 8; mk <<= 1) s += __shfl_xor(s, mk);
    invs[r] = 1.f / s;
    int il = 16*w + 4*lr + r;
    float mf = m_run[r];
    #pragma unroll
    for (int jtb = 0; jtb < 2; jtb++) {
      int jt = jtb * 16 + lc;
      float mv = (jtb == 0) ? mreg0[r] : mreg1[r];
      float fv = exp2f(mv - mf) * invs[r];
      fac_t[((size_t)z * 32 + jt) * NSEQ + i0 + il] = fv;
    }
  }
  #pragma unroll
  for (int nt = 0; nt < 4; nt++)
    #pragma unroll
    for (int r = 0; r < 4; r++) {
      int rw = i0 + 16*w + 4*lr + r;
      o1acc[((size_t)b * NSEQ + rw) * 512 + h * 64 + 16*nt + lc] = (f16)(o1a[nt][r] * invs[r]);
    }
}

// ---------------- pv2: out2[j,d] = sum_i attnT[j,i]*fac_t[jt,i]*v1[i,d] ----
// Grid (z, jt) XCD-local; Vs double-buffered (1 barrier/k-step).
__global__ __launch_bounds__(256) void pv2_k(const f16* __restrict__ attnT,
    const f16* __restrict__ v1t, const float* __restrict__ fac_t,
    f16* __restrict__ oacc, int bh0)
{
  __shared__ char vsm[16384];   // 2 x [64] swizzled rows: [d][k=i]
  int z = blockIdx.x, bh = bh0 + z, b = bh >> 3, h = bh & 7;
  int r0 = blockIdx.y * 64;     // j-block == jt index
  int tid = threadIdx.x, w = tid >> 6, lane = tid & 63;
  int lr = lane >> 4, lc = lane & 15;
  int row = tid >> 2, cv = (tid & 3) * 16;
  const f16* vp = v1t + ((size_t)bh * 64 + row) * NSEQ + cv;
  const float* fp = fac_t + ((size_t)z * 32 + blockIdx.y) * NSEQ + cv;
  const f16* ap = attnT + ((size_t)z * NSEQ + r0 + 16*w + lc) * NSEQ + 8*lr;
  f32x4 acc[4] = {};
  for (int k0 = 0; k0 < NSEQ; k0 += 64) {
    char* vb = vsm + (((k0 >> 6) & 1) << 13);
    f16x8 v0 = *(const f16x8*)(vp + k0);
    f16x8 v1 = *(const f16x8*)(vp + k0 + 8);
    float4 f0 = *(const float4*)(fp + k0),     f1 = *(const float4*)(fp + k0 + 4);
    float4 f2 = *(const float4*)(fp + k0 + 8), f3 = *(const float4*)(fp + k0 + 12);
    *(f16x8*)(vb + LSWZ(row, cv))     = scale8(v0, f0, f1);
    *(f16x8*)(vb + LSWZ(row, cv + 8)) = scale8(v1, f2, f3);
    __syncthreads();
    f16x8 a0 = *(const f16x8*)(ap + k0);
    f16x8 a1 = *(const f16x8*)(ap + k0 + 32);
    #pragma unroll
    for (int nt = 0; nt < 4; nt++) {
      acc[nt] = MFMA16(a0, *(const f16x8*)(vb + LSWZ(16*nt + lc, 8*lr)), acc[nt]);
      acc[nt] = MFMA16(a1, *(const f16x8*)(vb + LSWZ(16*nt + lc, 32 + 8*lr)), acc[nt]);
    }
  }
  #pragma unroll
  for (int nt = 0; nt < 4; nt++)
    #pragma unroll
    for (int r = 0; r < 4; r++) {
      int rw = r0 + 16*w + 4*lr + r;
      oacc[((size_t)b * NSEQ + rw) * 512 + h * 64 + 16*nt + lc] = (f16)acc[nt][r];
    }
}

extern "C" void kernel_launch(void* const* d_in, const int* in_sizes, int n_in,
                              void* d_out, int out_size, void* d_ws, size_t ws_size,
                              hipStream_t stream) {
  const float* x1   = (const float*)d_in[0];
  const float* x2   = (const float*)d_in[1];
  const float* Wq   = (const float*)d_in[2];
  const float* Wk   = (const float*)d_in[3];
  const float* Wv1  = (const float*)d_in[4];
  const float* Wv2  = (const float*)d_in[5];
  const float* Wrel = (const float*)d_in[6];
  const float* rpb  = (const float*)d_in[7];
  const float* Wo1  = (const float*)d_in[8];
  const float* bo1  = (const float*)d_in[9];
  const float* Wo2  = (const float*)d_in[10];
  const float* bo2  = (const float*)d_in[11];
  float* out = (float*)d_out;

  char* base = (char*)d_ws;
  size_t off = 0;
  auto alloc = [&](size_t bytes) -> void* {
    void* p = base + off; off += (bytes + 255) & ~(size_t)255; return p;
  };
  float* pos   = (float*)alloc((size_t)NPOS * 192 * 4);
  f16*   relq  = (f16*)  alloc((size_t)NH * NPOS * 64 * 2);
  f16*   qh    = (f16*)  alloc((size_t)16 * NSEQ * 64 * 2);
  f16*   kbh   = (f16*)  alloc((size_t)16 * NSEQ * 64 * 2);
  f16*   v1t   = (f16*)  alloc((size_t)16 * 64 * NSEQ * 2);
  f16*   v2t   = (f16*)  alloc((size_t)16 * 64 * NSEQ * 2);
  f16*   o1acc = (f16*)  alloc((size_t)2 * NSEQ * 512 * 2);
  f16*   o2acc = (f16*)  alloc((size_t)2 * NSEQ * 512 * 2);
  float* fac_t = (float*)alloc((size_t)16 * 32 * NSEQ * 4);
  f16*   Wqt   = (f16*)  alloc((size_t)512 * 1024 * 2);
  f16*   Wkt   = (f16*)  alloc((size_t)512 * 512 * 2);
  f16*   Wv1t  = (f16*)  alloc((size_t)512 * 1024 * 2);
  f16*   Wv2t  = (f16*)  alloc((size_t)512 * 512 * 2);
  f16*   Wrelt = (f16*)  alloc((size_t)512 * 192 * 2);
  f16*   Wo1t  = (f16*)  alloc((size_t)1024 * 512 * 2);
  f16*   Wo2t  = (f16*)  alloc((size_t)1024 * 512 * 2);
  size_t baseB = off;

  int chunk = 1;
  for (int c = 16; c >= 1; c >>= 1) {
    size_t needB = baseB + (size_t)c * NSEQ * NSEQ * 2;
    if (needB <= ws_size) { chunk = c; break; }
  }
  f16* attnT = (f16*)(base + baseB);

  pos_embed_k<<<(NPOS + 7) / 8, 256, 0, stream>>>(pos);
  wtrans_k<<<dim3(16, 16, 7), 256, 0, stream>>>(
      Wq, Wk, Wv1, Wv2, Wrel, Wo1, Wo2,
      Wqt, Wkt, Wv1t, Wv2t, Wrelt, Wo1t, Wo2t);
  relq_k<<<dim3(8, 32), 256, 0, stream>>>(pos, Wrelt, relq);
  projx_k<1024, false><<<dim3(16, 32), 256, 0, stream>>>(x1, Wqt, Wv1t, qh, v1t, nullptr);
  projx_k<512,  true ><<<dim3(16, 32), 256, 0, stream>>>(x2, Wkt, Wv2t, kbh, v2t, rpb);

  for (int bh0 = 0; bh0 < 16; bh0 += chunk) {
    attn_k<<<dim3(chunk, 32), 256, 0, stream>>>(qh, kbh, relq, v2t, attnT, fac_t, o1acc, bh0);
    pv2_k<<<dim3(chunk, 32), 256, 0, stream>>>(attnT, v1t, fac_t, o2acc, bh0);
  }

  outproj_k<<<dim3(16, 64), 256, 0, stream>>>(o1acc, o2acc, Wo1t, Wo2t, bo1, bo2, out);
}